// Round 3
// baseline (2018.902 us; speedup 1.0000x reference)
//
#include <hip/hip_runtime.h>
#include <cstddef>

#define NN 50000
#define EE 1600000

typedef unsigned short ushortT;
typedef short bf16x8 __attribute__((ext_vector_type(8)));
typedef float f32x4 __attribute__((ext_vector_type(4)));
typedef unsigned short us8 __attribute__((ext_vector_type(8)));

__device__ __forceinline__ ushortT f2bf(float x) {  // RNE float->bf16 bits
    unsigned u = __float_as_uint(x);
    u += 0x7fffu + ((u >> 16) & 1u);
    return (ushortT)(u >> 16);
}
__device__ __forceinline__ float bf2f(ushortT h) { return __uint_as_float(((unsigned)h) << 16); }

// ---------------- edge dtype canonicalization ----------------
__global__ void detect_i64_kernel(const int* __restrict__ ei, int* __restrict__ flag) {
    __shared__ int any;
    if (threadIdx.x == 0) any = 0;
    __syncthreads();
    for (int i = threadIdx.x; i < 8192; i += 256)
        if (ei[2 * i + 1] != 0) any = 1;   // benign race
    __syncthreads();
    if (threadIdx.x == 0) *flag = (any ? 0 : 1);  // 1 => int64 layout
}

__global__ void canon_edges_kernel(const int* __restrict__ ei, const int* __restrict__ flag,
                                   int* __restrict__ src32, int* __restrict__ dst32) {
    int e = blockIdx.x * blockDim.x + threadIdx.x;
    if (e >= EE) return;
    if (*flag) {
        src32[e] = ei[2 * e];
        dst32[e] = ei[2 * (EE + e)];
    } else {
        src32[e] = ei[e];
        dst32[e] = ei[EE + e];
    }
}

// ---------------- CSR build ----------------
__global__ void count_kernel(const int* __restrict__ dst, unsigned* __restrict__ counts) {
    int e = blockIdx.x * blockDim.x + threadIdx.x;
    if (e < EE) atomicAdd(&counts[dst[e]], 1u);
}

__global__ void dinv_kernel(const unsigned* __restrict__ counts, float* __restrict__ dinv) {
    int i = blockIdx.x * blockDim.x + threadIdx.x;
    if (i < NN) dinv[i] = rsqrtf((float)counts[i] + 1.0f);
}

__global__ void scan_kernel(const unsigned* __restrict__ counts, unsigned* __restrict__ row_ptr, int n) {
    __shared__ unsigned tmp[1024];
    __shared__ unsigned carry;
    if (threadIdx.x == 0) { carry = 0; row_ptr[0] = 0; }
    __syncthreads();
    for (int base = 0; base < n; base += 1024) {
        int i = base + (int)threadIdx.x;
        unsigned v = (i < n) ? counts[i] : 0u;
        tmp[threadIdx.x] = v;
        __syncthreads();
        for (int off = 1; off < 1024; off <<= 1) {
            unsigned addv = (threadIdx.x >= (unsigned)off) ? tmp[threadIdx.x - off] : 0u;
            __syncthreads();
            tmp[threadIdx.x] += addv;
            __syncthreads();
        }
        unsigned incl = tmp[threadIdx.x] + carry;
        if (i < n) row_ptr[i + 1] = incl;
        __syncthreads();
        if (threadIdx.x == 0) carry += tmp[1023];
        __syncthreads();
    }
}

__global__ void copy_u32_kernel(const unsigned* __restrict__ a, unsigned* __restrict__ b, int n) {
    int i = blockIdx.x * blockDim.x + threadIdx.x;
    if (i < n) b[i] = a[i];
}

__global__ void scatter_kernel(const int* __restrict__ src, const int* __restrict__ dst,
                               const float* __restrict__ dinv, unsigned* __restrict__ cursor,
                               int* __restrict__ col, float* __restrict__ nrm) {
    int e = blockIdx.x * blockDim.x + threadIdx.x;
    if (e >= EE) return;
    int d = dst[e], s = src[e];
    unsigned p = atomicAdd(&cursor[d], 1u);
    col[p] = s;
    nrm[p] = dinv[s] * dinv[d];
}

// ---------------- weight transpose + hi/lo bf16 split: W[K][N] -> WT[N][K] ----------------
__global__ void wconv_kernel(const float* __restrict__ W, ushortT* __restrict__ WTh,
                             ushortT* __restrict__ WTl, int K, int N) {
    int idx = blockIdx.x * 256 + threadIdx.x;
    if (idx >= K * N) return;
    int k = idx / N, n = idx - k * N;
    float w = W[idx];
    ushortT h = f2bf(w);
    ushortT l = f2bf(w - bf2f(h));
    WTh[(size_t)n * K + k] = h;
    WTl[(size_t)n * K + k] = l;
}

// ---------------- aggregation C=512, fp32 in -> bf16 hi/lo planes out ----------------
template <int RELU, int BIAS>
__global__ void aggregate512_kernel(const float* __restrict__ F,
                                    ushortT* __restrict__ Oh, ushortT* __restrict__ Ol,
                                    const unsigned* __restrict__ row_ptr, const int* __restrict__ col,
                                    const float* __restrict__ nrm, const float* __restrict__ dinv,
                                    const float* __restrict__ bias) {
    int node = blockIdx.x;
    int t = threadIdx.x;  // 128 threads x float4 = 512 ch
    float di = dinv[node];
    float dsl = di * di;
    float4 acc = ((const float4*)(F + (size_t)node * 512))[t];
    acc.x *= dsl; acc.y *= dsl; acc.z *= dsl; acc.w *= dsl;
    unsigned k = row_ptr[node], end = row_ptr[node + 1];
    for (; k + 2 <= end; k += 2) {
        int s0 = col[k], s1 = col[k + 1];
        float w0 = nrm[k], w1 = nrm[k + 1];
        float4 f0 = ((const float4*)(F + (size_t)s0 * 512))[t];
        float4 f1 = ((const float4*)(F + (size_t)s1 * 512))[t];
        acc.x += w0 * f0.x + w1 * f1.x;
        acc.y += w0 * f0.y + w1 * f1.y;
        acc.z += w0 * f0.z + w1 * f1.z;
        acc.w += w0 * f0.w + w1 * f1.w;
    }
    if (k < end) {
        int s0 = col[k];
        float w0 = nrm[k];
        float4 f0 = ((const float4*)(F + (size_t)s0 * 512))[t];
        acc.x += w0 * f0.x; acc.y += w0 * f0.y; acc.z += w0 * f0.z; acc.w += w0 * f0.w;
    }
    if (BIAS) {
        float4 bv = ((const float4*)bias)[t];
        acc.x += bv.x; acc.y += bv.y; acc.z += bv.z; acc.w += bv.w;
    }
    if (RELU) {
        acc.x = fmaxf(acc.x, 0.f); acc.y = fmaxf(acc.y, 0.f);
        acc.z = fmaxf(acc.z, 0.f); acc.w = fmaxf(acc.w, 0.f);
    }
    ushort4 h, l;
    h.x = f2bf(acc.x); l.x = f2bf(acc.x - bf2f(h.x));
    h.y = f2bf(acc.y); l.y = f2bf(acc.y - bf2f(h.y));
    h.z = f2bf(acc.z); l.z = f2bf(acc.z - bf2f(h.z));
    h.w = f2bf(acc.w); l.w = f2bf(acc.w - bf2f(h.w));
    ((ushort4*)(Oh + (size_t)node * 512))[t] = h;
    ((ushort4*)(Ol + (size_t)node * 512))[t] = l;
}

// ---------------- aggregation C=128 fp32->fp32 (layer 3) ----------------
template <int RELU, int BIAS>
__global__ void aggregate128_kernel(const float* __restrict__ F, float* __restrict__ O,
                                    const unsigned* __restrict__ row_ptr, const int* __restrict__ col,
                                    const float* __restrict__ nrm, const float* __restrict__ dinv,
                                    const float* __restrict__ bias) {
    int node = blockIdx.x;
    int tid = threadIdx.x;  // 128
    float di = dinv[node];
    float dsl = di * di;
    float acc = dsl * F[(size_t)node * 128 + tid];
    unsigned k = row_ptr[node], end = row_ptr[node + 1];
    for (; k + 2 <= end; k += 2) {
        int s0 = col[k], s1 = col[k + 1];
        float w0 = nrm[k], w1 = nrm[k + 1];
        acc += w0 * F[(size_t)s0 * 128 + tid] + w1 * F[(size_t)s1 * 128 + tid];
    }
    if (k < end) acc += nrm[k] * F[(size_t)col[k] * 128 + tid];
    if (BIAS) acc += bias[tid];
    if (RELU) acc = fmaxf(acc, 0.f);
    O[(size_t)node * 128 + tid] = acc;
}

// ---------------- bf16x3-split MFMA GEMM ----------------
// C[M,N] = A[M,K] @ B[K,N] with A given as hi/lo bf16 planes [M][K] and
// B given as W^T hi/lo planes [N][K]. 128x128 tile, BK=32, 4 waves (2x2),
// each wave 64x64 = 4x4 tiles of mfma_f32_16x16x32_bf16, 3 MFMAs per tile
// (ah*bh + ah*bl + al*bh). K-slot assignment k = (lane>>4)*8 + j applied
// identically to A and B => K-permutation-invariant => only relies on the
// verified C/D layout (col=lane&15, row=(lane>>4)*4+reg, m89/m91).
template <int OUTMODE, int RELU, int BIAS>  // OUTMODE 0: fp32 C, 1: bf16 hi/lo planes
__global__ __launch_bounds__(256) void gemm_mfma_kernel(
    const ushortT* __restrict__ Ah, const ushortT* __restrict__ Al,
    const ushortT* __restrict__ Bh, const ushortT* __restrict__ Bl,
    const float* __restrict__ bias,
    float* __restrict__ Cf, ushortT* __restrict__ Ch, ushortT* __restrict__ Cl,
    int M, int N, int K) {
    __shared__ ushortT As[2][128][40];  // [plane][row][k], 80B row stride (5x16B)
    __shared__ ushortT Bs[2][128][40];
    int tid = threadIdx.x;
    int lane = tid & 63, wave = tid >> 6;
    int wr = wave >> 1, wc = wave & 1;
    int bm = blockIdx.y * 128, bn = blockIdx.x * 128;
    int srow = tid >> 1;           // staging row/col 0..127
    int shalf = (tid & 1) * 16;    // k offset 0/16
    int kg = lane >> 4, lr = lane & 15;

    f32x4 zero4 = {0.f, 0.f, 0.f, 0.f};
    f32x4 acc[4][4];
#pragma unroll
    for (int i = 0; i < 4; i++)
#pragma unroll
        for (int j = 0; j < 4; j++) acc[i][j] = zero4;

    int gm_st = bm + srow;
    const ushortT* pAh = Ah + (size_t)gm_st * K + shalf;
    const ushortT* pAl = Al + (size_t)gm_st * K + shalf;
    const ushortT* pBh = Bh + (size_t)(bn + srow) * K + shalf;
    const ushortT* pBl = Bl + (size_t)(bn + srow) * K + shalf;

    for (int k0 = 0; k0 < K; k0 += 32) {
        us8 ah0 = {0,0,0,0,0,0,0,0}, ah1 = ah0, al0 = ah0, al1 = ah0;
        if (gm_st < M) {
            ah0 = *(const us8*)(pAh + k0);
            ah1 = *(const us8*)(pAh + k0 + 8);
            al0 = *(const us8*)(pAl + k0);
            al1 = *(const us8*)(pAl + k0 + 8);
        }
        us8 bh0 = *(const us8*)(pBh + k0);
        us8 bh1 = *(const us8*)(pBh + k0 + 8);
        us8 bl0 = *(const us8*)(pBl + k0);
        us8 bl1 = *(const us8*)(pBl + k0 + 8);
        __syncthreads();  // previous iteration's ds_reads done
        *(us8*)&As[0][srow][shalf] = ah0;
        *(us8*)&As[0][srow][shalf + 8] = ah1;
        *(us8*)&As[1][srow][shalf] = al0;
        *(us8*)&As[1][srow][shalf + 8] = al1;
        *(us8*)&Bs[0][srow][shalf] = bh0;
        *(us8*)&Bs[0][srow][shalf + 8] = bh1;
        *(us8*)&Bs[1][srow][shalf] = bl0;
        *(us8*)&Bs[1][srow][shalf + 8] = bl1;
        __syncthreads();

        bf16x8 afh[4], afl[4], bfh[4], bfl[4];
#pragma unroll
        for (int i = 0; i < 4; i++) {
            int r = wr * 64 + i * 16 + lr;
            afh[i] = *(const bf16x8*)&As[0][r][kg * 8];
            afl[i] = *(const bf16x8*)&As[1][r][kg * 8];
        }
#pragma unroll
        for (int j = 0; j < 4; j++) {
            int c = wc * 64 + j * 16 + lr;
            bfh[j] = *(const bf16x8*)&Bs[0][c][kg * 8];
            bfl[j] = *(const bf16x8*)&Bs[1][c][kg * 8];
        }
#pragma unroll
        for (int i = 0; i < 4; i++)
#pragma unroll
            for (int j = 0; j < 4; j++) {
                acc[i][j] = __builtin_amdgcn_mfma_f32_16x16x32_bf16(afh[i], bfh[j], acc[i][j], 0, 0, 0);
                acc[i][j] = __builtin_amdgcn_mfma_f32_16x16x32_bf16(afh[i], bfl[j], acc[i][j], 0, 0, 0);
                acc[i][j] = __builtin_amdgcn_mfma_f32_16x16x32_bf16(afl[i], bfh[j], acc[i][j], 0, 0, 0);
            }
    }

#pragma unroll
    for (int i = 0; i < 4; i++)
#pragma unroll
        for (int j = 0; j < 4; j++) {
            int gn = bn + wc * 64 + j * 16 + lr;
            float bv = BIAS ? bias[gn] : 0.f;
#pragma unroll
            for (int reg = 0; reg < 4; reg++) {
                int gm = bm + wr * 64 + i * 16 + kg * 4 + reg;
                if (gm < M) {
                    float v = acc[i][j][reg] + bv;
                    if (RELU) v = fmaxf(v, 0.f);
                    if (OUTMODE == 0) {
                        Cf[(size_t)gm * N + gn] = v;
                    } else {
                        ushortT h = f2bf(v);
                        Ch[(size_t)gm * N + gn] = h;
                        Cl[(size_t)gm * N + gn] = f2bf(v - bf2f(h));
                    }
                }
            }
        }
}

// ---------------- FC 128->10 + log_softmax ----------------
__global__ void fc_logsoftmax_kernel(const float* __restrict__ H, const float* __restrict__ Wfc,
                                     const float* __restrict__ bfc, float* __restrict__ out, int M) {
    int wid = threadIdx.x >> 6;
    int lane = threadIdx.x & 63;
    int node = blockIdx.x * 4 + wid;
    if (node >= M) return;
    const float* h = H + (size_t)node * 128;
    float d0 = h[lane], d1 = h[lane + 64];
    float lg[10];
#pragma unroll
    for (int c = 0; c < 10; c++) {
        float s = d0 * Wfc[lane * 10 + c] + d1 * Wfc[(lane + 64) * 10 + c];
#pragma unroll
        for (int o = 1; o < 64; o <<= 1) s += __shfl_xor(s, o, 64);
        lg[c] = s + bfc[c];
    }
    float mx = lg[0];
#pragma unroll
    for (int c = 1; c < 10; c++) mx = fmaxf(mx, lg[c]);
    float se = 0.f;
#pragma unroll
    for (int c = 0; c < 10; c++) se += expf(lg[c] - mx);
    float lse = logf(se) + mx;
    if (lane < 10) {
        float v = 0.f;
#pragma unroll
        for (int c = 0; c < 10; c++)
            if (lane == c) v = lg[c];
        out[(size_t)node * 10 + lane] = v - lse;
    }
}

extern "C" void kernel_launch(void* const* d_in, const int* in_sizes, int n_in,
                              void* d_out, int out_size, void* d_ws, size_t ws_size,
                              hipStream_t stream) {
    const float* x   = (const float*)d_in[0];
    const int*   ei  = (const int*)d_in[1];
    const float* W1  = (const float*)d_in[2];
    const float* b1  = (const float*)d_in[3];
    const float* W2  = (const float*)d_in[4];
    const float* b2  = (const float*)d_in[5];
    const float* W3  = (const float*)d_in[6];
    const float* b3  = (const float*)d_in[7];
    const float* Wfc = (const float*)d_in[8];
    const float* bfc = (const float*)d_in[9];
    float* out = (float*)d_out;

    char* ws = (char*)d_ws;
    size_t off = 0;
    auto alloc = [&](size_t bytes) -> void* {
        void* p = ws + off;
        off = (off + bytes + 255) & ~(size_t)255;
        return p;
    };
    int*      flag    = (int*)alloc(4);
    unsigned* counts  = (unsigned*)alloc((size_t)NN * 4);
    unsigned* row_ptr = (unsigned*)alloc((size_t)(NN + 1) * 4);
    unsigned* cursor  = (unsigned*)alloc((size_t)NN * 4);
    float*    dinv    = (float*)alloc((size_t)NN * 4);
    int*      src32   = (int*)alloc((size_t)EE * 4);
    int*      dst32   = (int*)alloc((size_t)EE * 4);
    int*      col     = (int*)alloc((size_t)EE * 4);
    float*    nrm     = (float*)alloc((size_t)EE * 4);
    ushortT*  W1Th    = (ushortT*)alloc((size_t)1024 * 512 * 2);
    ushortT*  W1Tl    = (ushortT*)alloc((size_t)1024 * 512 * 2);
    ushortT*  W2Th    = (ushortT*)alloc((size_t)512 * 1024 * 2);
    ushortT*  W2Tl    = (ushortT*)alloc((size_t)512 * 1024 * 2);
    ushortT*  W3Th    = (ushortT*)alloc((size_t)128 * 512 * 2);
    ushortT*  W3Tl    = (ushortT*)alloc((size_t)128 * 512 * 2);
    char*     bufA    = (char*)alloc((size_t)NN * 1024 * 2 * 2);  // 204.8 MB
    char*     bufB    = (char*)alloc((size_t)NN * 512 * 4);       // 102.4 MB

    // aliased views (sequential lifetimes, see journal):
    ushortT* P1h = (ushortT*)bufB;                 // agg1 out planes [NN][512]
    ushortT* P1l = P1h + (size_t)NN * 512;
    ushortT* Q1h = (ushortT*)bufA;                 // gemm1 out planes [NN][1024]
    ushortT* Q1l = Q1h + (size_t)NN * 1024;
    float*   G2f = (float*)bufB;                   // gemm2 out fp32 [NN][512]
    ushortT* P2h = (ushortT*)bufA;                 // agg2 out planes [NN][512]
    ushortT* P2l = P2h + (size_t)NN * 512;
    float*   G3f = (float*)bufB;                   // gemm3 out fp32 [NN][128]
    float*   D2  = (float*)bufA;                   // agg3 out fp32 [NN][128]

    // --- weight conversion (W -> W^T hi/lo bf16) ---
    wconv_kernel<<<(512 * 1024 + 255) / 256, 256, 0, stream>>>(W1, W1Th, W1Tl, 512, 1024);
    wconv_kernel<<<(1024 * 512 + 255) / 256, 256, 0, stream>>>(W2, W2Th, W2Tl, 1024, 512);
    wconv_kernel<<<(512 * 128 + 255) / 256, 256, 0, stream>>>(W3, W3Th, W3Tl, 512, 128);

    // --- edges + CSR ---
    hipMemsetAsync(counts, 0, (size_t)NN * 4, stream);
    detect_i64_kernel<<<1, 256, 0, stream>>>(ei, flag);
    canon_edges_kernel<<<(EE + 255) / 256, 256, 0, stream>>>(ei, flag, src32, dst32);
    count_kernel<<<(EE + 255) / 256, 256, 0, stream>>>(dst32, counts);
    dinv_kernel<<<(NN + 255) / 256, 256, 0, stream>>>(counts, dinv);
    scan_kernel<<<1, 1024, 0, stream>>>(counts, row_ptr, NN);
    copy_u32_kernel<<<(NN + 255) / 256, 256, 0, stream>>>(row_ptr, cursor, NN);
    scatter_kernel<<<(EE + 255) / 256, 256, 0, stream>>>(src32, dst32, dinv, cursor, col, nrm);

    const int GY = (NN + 127) / 128;  // 391

    // --- layer 1: P1 = A_hat @ x ; Q1 = relu(P1 @ W1 + b1) ---
    aggregate512_kernel<0, 0><<<NN, 128, 0, stream>>>(x, P1h, P1l, row_ptr, col, nrm, dinv, nullptr);
    gemm_mfma_kernel<1, 1, 1><<<dim3(1024 / 128, GY), 256, 0, stream>>>(
        P1h, P1l, W1Th, W1Tl, b1, nullptr, Q1h, Q1l, NN, 1024, 512);

    // --- layer 2: G2 = Q1 @ W2 ; P2 = relu(A_hat @ G2 + b2) ---
    gemm_mfma_kernel<0, 0, 0><<<dim3(512 / 128, GY), 256, 0, stream>>>(
        Q1h, Q1l, W2Th, W2Tl, nullptr, G2f, nullptr, nullptr, NN, 512, 1024);
    aggregate512_kernel<1, 1><<<NN, 128, 0, stream>>>(G2f, P2h, P2l, row_ptr, col, nrm, dinv, b2);

    // --- layer 3: G3 = P2 @ W3 ; D2 = relu(A_hat @ G3 + b3) ---
    gemm_mfma_kernel<0, 0, 0><<<dim3(128 / 128, GY), 256, 0, stream>>>(
        P2h, P2l, W3Th, W3Tl, nullptr, G3f, nullptr, nullptr, NN, 128, 512);
    aggregate128_kernel<1, 1><<<NN, 128, 0, stream>>>(G3f, D2, row_ptr, col, nrm, dinv, b3);

    // --- FC + log_softmax ---
    fc_logsoftmax_kernel<<<(NN + 3) / 4, 256, 0, stream>>>(D2, Wfc, bfc, out, NN);
}

// Round 5
// 1883.644 us; speedup vs baseline: 1.0718x; 1.0718x over previous
//
#include <hip/hip_runtime.h>
#include <cstddef>

#define NN 50000
#define EE 1600000

typedef unsigned short ushortT;
typedef short bf16x8 __attribute__((ext_vector_type(8)));
typedef float f32x4 __attribute__((ext_vector_type(4)));
typedef unsigned short us8 __attribute__((ext_vector_type(8)));

__device__ __forceinline__ ushortT f2bf(float x) {  // RNE float->bf16 bits
    unsigned u = __float_as_uint(x);
    u += 0x7fffu + ((u >> 16) & 1u);
    return (ushortT)(u >> 16);
}
__device__ __forceinline__ float bf2f(ushortT h) { return __uint_as_float(((unsigned)h) << 16); }

// ---------------- edge dtype canonicalization ----------------
__global__ void detect_i64_kernel(const int* __restrict__ ei, int* __restrict__ flag) {
    __shared__ int any;
    if (threadIdx.x == 0) any = 0;
    __syncthreads();
    for (int i = threadIdx.x; i < 8192; i += 256)
        if (ei[2 * i + 1] != 0) any = 1;   // benign race
    __syncthreads();
    if (threadIdx.x == 0) *flag = (any ? 0 : 1);  // 1 => int64 layout
}

__global__ void canon_edges_kernel(const int* __restrict__ ei, const int* __restrict__ flag,
                                   int* __restrict__ src32, int* __restrict__ dst32) {
    int e = blockIdx.x * blockDim.x + threadIdx.x;
    if (e >= EE) return;
    if (*flag) {
        src32[e] = ei[2 * e];
        dst32[e] = ei[2 * (EE + e)];
    } else {
        src32[e] = ei[e];
        dst32[e] = ei[EE + e];
    }
}

// ---------------- CSR build ----------------
__global__ void count_kernel(const int* __restrict__ dst, unsigned* __restrict__ counts) {
    int e = blockIdx.x * blockDim.x + threadIdx.x;
    if (e < EE) atomicAdd(&counts[dst[e]], 1u);
}

__global__ void dinv_kernel(const unsigned* __restrict__ counts, float* __restrict__ dinv) {
    int i = blockIdx.x * blockDim.x + threadIdx.x;
    if (i < NN) dinv[i] = rsqrtf((float)counts[i] + 1.0f);
}

// 3-kernel parallel scan over counts[0..n) -> row_ptr (exclusive+1) and cursor
__global__ void scan_part_kernel(const unsigned* __restrict__ counts, unsigned* __restrict__ part, int n) {
    __shared__ unsigned s[256];
    int i = blockIdx.x * 256 + threadIdx.x;
    s[threadIdx.x] = (i < n) ? counts[i] : 0u;
    __syncthreads();
    for (int off = 128; off > 0; off >>= 1) {
        if (threadIdx.x < (unsigned)off) s[threadIdx.x] += s[threadIdx.x + off];
        __syncthreads();
    }
    if (threadIdx.x == 0) part[blockIdx.x] = s[0];
}

__global__ void scan_base_kernel(unsigned* __restrict__ part, int nb) {
    __shared__ unsigned s[256];
    int t = threadIdx.x;
    unsigned v = (t < nb) ? part[t] : 0u;
    s[t] = v;
    __syncthreads();
    for (int off = 1; off < 256; off <<= 1) {
        unsigned a = (t >= off) ? s[t - off] : 0u;
        __syncthreads();
        s[t] += a;
        __syncthreads();
    }
    if (t < nb) part[t] = s[t] - v;  // exclusive
}

__global__ void scan_final_kernel(const unsigned* __restrict__ counts, const unsigned* __restrict__ part,
                                  unsigned* __restrict__ row_ptr, unsigned* __restrict__ cursor, int n) {
    __shared__ unsigned s[256];
    int b = blockIdx.x, t = threadIdx.x;
    int i = b * 256 + t;
    unsigned v = (i < n) ? counts[i] : 0u;
    s[t] = v;
    __syncthreads();
    for (int off = 1; off < 256; off <<= 1) {
        unsigned a = (t >= off) ? s[t - off] : 0u;
        __syncthreads();
        s[t] += a;
        __syncthreads();
    }
    if (i < n) {
        unsigned incl = s[t] + part[b];
        row_ptr[i + 1] = incl;
        cursor[i] = incl - v;
    }
    if (i == 0) row_ptr[0] = 0;
}

// edge record: x = src node, y = float bits of norm weight
__global__ void scatter_kernel(const int* __restrict__ src, const int* __restrict__ dst,
                               const float* __restrict__ dinv, unsigned* __restrict__ cursor,
                               uint2* __restrict__ ed) {
    int e = blockIdx.x * blockDim.x + threadIdx.x;
    if (e >= EE) return;
    int d = dst[e], s = src[e];
    unsigned p = atomicAdd(&cursor[d], 1u);
    uint2 r;
    r.x = (unsigned)s;
    r.y = __float_as_uint(dinv[s] * dinv[d]);
    ed[p] = r;
}

// ---------------- weight transpose + hi/lo bf16 split: W[K][N] -> WT[N][K] ----------------
__global__ void wconv_kernel(const float* __restrict__ W, ushortT* __restrict__ WTh,
                             ushortT* __restrict__ WTl, int K, int N) {
    int idx = blockIdx.x * 256 + threadIdx.x;
    if (idx >= K * N) return;
    int k = idx / N, n = idx - k * N;
    float w = W[idx];
    ushortT h = f2bf(w);
    ushortT l = f2bf(w - bf2f(h));
    WTh[(size_t)n * K + k] = h;
    WTl[(size_t)n * K + k] = l;
}

// ---------------- aggregation C=512 (8-edge ILP batches), fp32 in -> bf16 hi/lo out ----------------
template <int RELU, int BIAS>
__global__ void aggregate512_kernel(const float* __restrict__ F,
                                    ushortT* __restrict__ Oh, ushortT* __restrict__ Ol,
                                    const unsigned* __restrict__ row_ptr, const uint2* __restrict__ ed,
                                    const float* __restrict__ dinv, const float* __restrict__ bias) {
    int node = blockIdx.x;
    int t = threadIdx.x;  // 128 threads x float4 = 512 ch
    float di = dinv[node];
    float dsl = di * di;
    float4 acc = ((const float4*)(F + (size_t)node * 512))[t];
    acc.x *= dsl; acc.y *= dsl; acc.z *= dsl; acc.w *= dsl;
    unsigned k = row_ptr[node], end = row_ptr[node + 1];
    for (; k + 8 <= end; k += 8) {
        uint2 e[8];
#pragma unroll
        for (int j = 0; j < 8; j++) e[j] = ed[k + j];
        float4 f[8];
#pragma unroll
        for (int j = 0; j < 8; j++) f[j] = ((const float4*)(F + (size_t)e[j].x * 512))[t];
#pragma unroll
        for (int j = 0; j < 8; j++) {
            float w = __uint_as_float(e[j].y);
            acc.x += w * f[j].x;
            acc.y += w * f[j].y;
            acc.z += w * f[j].z;
            acc.w += w * f[j].w;
        }
    }
    for (; k < end; k++) {
        uint2 e = ed[k];
        float w = __uint_as_float(e.y);
        float4 f = ((const float4*)(F + (size_t)e.x * 512))[t];
        acc.x += w * f.x; acc.y += w * f.y; acc.z += w * f.z; acc.w += w * f.w;
    }
    if (BIAS) {
        float4 bv = ((const float4*)bias)[t];
        acc.x += bv.x; acc.y += bv.y; acc.z += bv.z; acc.w += bv.w;
    }
    if (RELU) {
        acc.x = fmaxf(acc.x, 0.f); acc.y = fmaxf(acc.y, 0.f);
        acc.z = fmaxf(acc.z, 0.f); acc.w = fmaxf(acc.w, 0.f);
    }
    ushort4 h, l;
    h.x = f2bf(acc.x); l.x = f2bf(acc.x - bf2f(h.x));
    h.y = f2bf(acc.y); l.y = f2bf(acc.y - bf2f(h.y));
    h.z = f2bf(acc.z); l.z = f2bf(acc.z - bf2f(h.z));
    h.w = f2bf(acc.w); l.w = f2bf(acc.w - bf2f(h.w));
    ((ushort4*)(Oh + (size_t)node * 512))[t] = h;
    ((ushort4*)(Ol + (size_t)node * 512))[t] = l;
}

// ---------------- aggregation C=128 (one wave per node, float2/lane, 8-edge batches) ----------------
template <int RELU, int BIAS>
__global__ void aggregate128_kernel(const float* __restrict__ F, float* __restrict__ O,
                                    const unsigned* __restrict__ row_ptr, const uint2* __restrict__ ed,
                                    const float* __restrict__ dinv, const float* __restrict__ bias) {
    int wid = threadIdx.x >> 6;
    int lane = threadIdx.x & 63;
    int node = blockIdx.x * 4 + wid;
    if (node >= NN) return;
    float di = dinv[node];
    float dsl = di * di;
    float2 acc = ((const float2*)(F + (size_t)node * 128))[lane];
    acc.x *= dsl; acc.y *= dsl;
    unsigned k = row_ptr[node], end = row_ptr[node + 1];
    for (; k + 8 <= end; k += 8) {
        uint2 e[8];
#pragma unroll
        for (int j = 0; j < 8; j++) e[j] = ed[k + j];
        float2 f[8];
#pragma unroll
        for (int j = 0; j < 8; j++) f[j] = ((const float2*)(F + (size_t)e[j].x * 128))[lane];
#pragma unroll
        for (int j = 0; j < 8; j++) {
            float w = __uint_as_float(e[j].y);
            acc.x += w * f[j].x;
            acc.y += w * f[j].y;
        }
    }
    for (; k < end; k++) {
        uint2 e = ed[k];
        float w = __uint_as_float(e.y);
        float2 f = ((const float2*)(F + (size_t)e.x * 128))[lane];
        acc.x += w * f.x; acc.y += w * f.y;
    }
    if (BIAS) {
        float2 bv = ((const float2*)bias)[lane];
        acc.x += bv.x; acc.y += bv.y;
    }
    if (RELU) { acc.x = fmaxf(acc.x, 0.f); acc.y = fmaxf(acc.y, 0.f); }
    ((float2*)(O + (size_t)node * 128))[lane] = acc;
}

// ---------------- bf16x3-split MFMA GEMM (validated r3) ----------------
template <int OUTMODE, int RELU, int BIAS>  // OUTMODE 0: fp32 C, 1: bf16 hi/lo planes
__global__ __launch_bounds__(256) void gemm_mfma_kernel(
    const ushortT* __restrict__ Ah, const ushortT* __restrict__ Al,
    const ushortT* __restrict__ Bh, const ushortT* __restrict__ Bl,
    const float* __restrict__ bias,
    float* __restrict__ Cf, ushortT* __restrict__ Ch, ushortT* __restrict__ Cl,
    int M, int N, int K) {
    __shared__ ushortT As[2][128][40];  // [plane][row][k], 80B row stride
    __shared__ ushortT Bs[2][128][40];
    int tid = threadIdx.x;
    int lane = tid & 63, wave = tid >> 6;
    int wr = wave >> 1, wc = wave & 1;
    int bm = blockIdx.y * 128, bn = blockIdx.x * 128;
    int srow = tid >> 1;
    int shalf = (tid & 1) * 16;
    int kg = lane >> 4, lr = lane & 15;

    f32x4 zero4 = {0.f, 0.f, 0.f, 0.f};
    f32x4 acc[4][4];
#pragma unroll
    for (int i = 0; i < 4; i++)
#pragma unroll
        for (int j = 0; j < 4; j++) acc[i][j] = zero4;

    int gm_st = bm + srow;
    const ushortT* pAh = Ah + (size_t)gm_st * K + shalf;
    const ushortT* pAl = Al + (size_t)gm_st * K + shalf;
    const ushortT* pBh = Bh + (size_t)(bn + srow) * K + shalf;
    const ushortT* pBl = Bl + (size_t)(bn + srow) * K + shalf;

    for (int k0 = 0; k0 < K; k0 += 32) {
        us8 ah0 = {0,0,0,0,0,0,0,0}, ah1 = ah0, al0 = ah0, al1 = ah0;
        if (gm_st < M) {
            ah0 = *(const us8*)(pAh + k0);
            ah1 = *(const us8*)(pAh + k0 + 8);
            al0 = *(const us8*)(pAl + k0);
            al1 = *(const us8*)(pAl + k0 + 8);
        }
        us8 bh0 = *(const us8*)(pBh + k0);
        us8 bh1 = *(const us8*)(pBh + k0 + 8);
        us8 bl0 = *(const us8*)(pBl + k0);
        us8 bl1 = *(const us8*)(pBl + k0 + 8);
        __syncthreads();
        *(us8*)&As[0][srow][shalf] = ah0;
        *(us8*)&As[0][srow][shalf + 8] = ah1;
        *(us8*)&As[1][srow][shalf] = al0;
        *(us8*)&As[1][srow][shalf + 8] = al1;
        *(us8*)&Bs[0][srow][shalf] = bh0;
        *(us8*)&Bs[0][srow][shalf + 8] = bh1;
        *(us8*)&Bs[1][srow][shalf] = bl0;
        *(us8*)&Bs[1][srow][shalf + 8] = bl1;
        __syncthreads();

        bf16x8 afh[4], afl[4], bfh[4], bfl[4];
#pragma unroll
        for (int i = 0; i < 4; i++) {
            int r = wr * 64 + i * 16 + lr;
            afh[i] = *(const bf16x8*)&As[0][r][kg * 8];
            afl[i] = *(const bf16x8*)&As[1][r][kg * 8];
        }
#pragma unroll
        for (int j = 0; j < 4; j++) {
            int c = wc * 64 + j * 16 + lr;
            bfh[j] = *(const bf16x8*)&Bs[0][c][kg * 8];
            bfl[j] = *(const bf16x8*)&Bs[1][c][kg * 8];
        }
#pragma unroll
        for (int i = 0; i < 4; i++)
#pragma unroll
            for (int j = 0; j < 4; j++) {
                acc[i][j] = __builtin_amdgcn_mfma_f32_16x16x32_bf16(afh[i], bfh[j], acc[i][j], 0, 0, 0);
                acc[i][j] = __builtin_amdgcn_mfma_f32_16x16x32_bf16(afh[i], bfl[j], acc[i][j], 0, 0, 0);
                acc[i][j] = __builtin_amdgcn_mfma_f32_16x16x32_bf16(afl[i], bfh[j], acc[i][j], 0, 0, 0);
            }
    }

#pragma unroll
    for (int i = 0; i < 4; i++)
#pragma unroll
        for (int j = 0; j < 4; j++) {
            int gn = bn + wc * 64 + j * 16 + lr;
            float bv = BIAS ? bias[gn] : 0.f;
#pragma unroll
            for (int reg = 0; reg < 4; reg++) {
                int gm = bm + wr * 64 + i * 16 + kg * 4 + reg;
                if (gm < M) {
                    float v = acc[i][j][reg] + bv;
                    if (RELU) v = fmaxf(v, 0.f);
                    if (OUTMODE == 0) {
                        Cf[(size_t)gm * N + gn] = v;
                    } else {
                        ushortT h = f2bf(v);
                        Ch[(size_t)gm * N + gn] = h;
                        Cl[(size_t)gm * N + gn] = f2bf(v - bf2f(h));
                    }
                }
            }
        }
}

// ---------------- FC 128->10 + log_softmax ----------------
__global__ void fc_logsoftmax_kernel(const float* __restrict__ H, const float* __restrict__ Wfc,
                                     const float* __restrict__ bfc, float* __restrict__ out, int M) {
    int wid = threadIdx.x >> 6;
    int lane = threadIdx.x & 63;
    int node = blockIdx.x * 4 + wid;
    if (node >= M) return;
    const float* h = H + (size_t)node * 128;
    float d0 = h[lane], d1 = h[lane + 64];
    float lg[10];
#pragma unroll
    for (int c = 0; c < 10; c++) {
        float s = d0 * Wfc[lane * 10 + c] + d1 * Wfc[(lane + 64) * 10 + c];
#pragma unroll
        for (int o = 1; o < 64; o <<= 1) s += __shfl_xor(s, o, 64);
        lg[c] = s + bfc[c];
    }
    float mx = lg[0];
#pragma unroll
    for (int c = 1; c < 10; c++) mx = fmaxf(mx, lg[c]);
    float se = 0.f;
#pragma unroll
    for (int c = 0; c < 10; c++) se += expf(lg[c] - mx);
    float lse = logf(se) + mx;
    if (lane < 10) {
        float v = 0.f;
#pragma unroll
        for (int c = 0; c < 10; c++)
            if (lane == c) v = lg[c];
        out[(size_t)node * 10 + lane] = v - lse;
    }
}

extern "C" void kernel_launch(void* const* d_in, const int* in_sizes, int n_in,
                              void* d_out, int out_size, void* d_ws, size_t ws_size,
                              hipStream_t stream) {
    const float* x   = (const float*)d_in[0];
    const int*   ei  = (const int*)d_in[1];
    const float* W1  = (const float*)d_in[2];
    const float* b1  = (const float*)d_in[3];
    const float* W2  = (const float*)d_in[4];
    const float* b2  = (const float*)d_in[5];
    const float* W3  = (const float*)d_in[6];
    const float* b3  = (const float*)d_in[7];
    const float* Wfc = (const float*)d_in[8];
    const float* bfc = (const float*)d_in[9];
    float* out = (float*)d_out;

    char* ws = (char*)d_ws;
    size_t off = 0;
    auto alloc = [&](size_t bytes) -> void* {
        void* p = ws + off;
        off = (off + bytes + 255) & ~(size_t)255;
        return p;
    };
    int*      flag    = (int*)alloc(4);
    unsigned* counts  = (unsigned*)alloc((size_t)NN * 4);
    unsigned* row_ptr = (unsigned*)alloc((size_t)(NN + 1) * 4);
    unsigned* cursor  = (unsigned*)alloc((size_t)NN * 4);
    unsigned* part    = (unsigned*)alloc((size_t)256 * 4);
    float*    dinv    = (float*)alloc((size_t)NN * 4);
    int*      src32   = (int*)alloc((size_t)EE * 4);
    int*      dst32   = (int*)alloc((size_t)EE * 4);
    uint2*    ed      = (uint2*)alloc((size_t)EE * 8);
    ushortT*  W1Th    = (ushortT*)alloc((size_t)1024 * 512 * 2);
    ushortT*  W1Tl    = (ushortT*)alloc((size_t)1024 * 512 * 2);
    ushortT*  W2Th    = (ushortT*)alloc((size_t)512 * 1024 * 2);
    ushortT*  W2Tl    = (ushortT*)alloc((size_t)512 * 1024 * 2);
    ushortT*  W3Th    = (ushortT*)alloc((size_t)128 * 512 * 2);
    ushortT*  W3Tl    = (ushortT*)alloc((size_t)128 * 512 * 2);
    char*     bufA    = (char*)alloc((size_t)NN * 1024 * 2 * 2);  // 204.8 MB
    char*     bufB    = (char*)alloc((size_t)NN * 512 * 4);       // 102.4 MB

    // aliased views (sequential lifetimes):
    ushortT* P1h = (ushortT*)bufB;                 // agg1 out planes [NN][512]
    ushortT* P1l = P1h + (size_t)NN * 512;
    ushortT* Q1h = (ushortT*)bufA;                 // gemm1 out planes [NN][1024]
    ushortT* Q1l = Q1h + (size_t)NN * 1024;
    float*   G2f = (float*)bufB;                   // gemm2 out fp32 [NN][512]
    ushortT* P2h = (ushortT*)bufA;                 // agg2 out planes [NN][512]
    ushortT* P2l = P2h + (size_t)NN * 512;
    float*   G3f = (float*)bufB;                   // gemm3 out fp32 [NN][128]
    float*   D2  = (float*)bufA;                   // agg3 out fp32 [NN][128]

    // --- weight conversion ---
    wconv_kernel<<<(512 * 1024 + 255) / 256, 256, 0, stream>>>(W1, W1Th, W1Tl, 512, 1024);
    wconv_kernel<<<(1024 * 512 + 255) / 256, 256, 0, stream>>>(W2, W2Th, W2Tl, 1024, 512);
    wconv_kernel<<<(512 * 128 + 255) / 256, 256, 0, stream>>>(W3, W3Th, W3Tl, 512, 128);

    // --- edges + CSR ---
    hipMemsetAsync(counts, 0, (size_t)NN * 4, stream);
    detect_i64_kernel<<<1, 256, 0, stream>>>(ei, flag);
    canon_edges_kernel<<<(EE + 255) / 256, 256, 0, stream>>>(ei, flag, src32, dst32);
    count_kernel<<<(EE + 255) / 256, 256, 0, stream>>>(dst32, counts);
    dinv_kernel<<<(NN + 255) / 256, 256, 0, stream>>>(counts, dinv);
    const int NB = (NN + 255) / 256;  // 196
    scan_part_kernel<<<NB, 256, 0, stream>>>(counts, part, NN);
    scan_base_kernel<<<1, 256, 0, stream>>>(part, NB);
    scan_final_kernel<<<NB, 256, 0, stream>>>(counts, part, row_ptr, cursor, NN);
    scatter_kernel<<<(EE + 255) / 256, 256, 0, stream>>>(src32, dst32, dinv, cursor, ed);

    const int GY = (NN + 127) / 128;  // 391

    // --- layer 1: P1 = A_hat @ x ; Q1 = relu(P1 @ W1 + b1) ---
    aggregate512_kernel<0, 0><<<NN, 128, 0, stream>>>(x, P1h, P1l, row_ptr, ed, dinv, nullptr);
    gemm_mfma_kernel<1, 1, 1><<<dim3(1024 / 128, GY), 256, 0, stream>>>(
        P1h, P1l, W1Th, W1Tl, b1, nullptr, Q1h, Q1l, NN, 1024, 512);

    // --- layer 2: G2 = Q1 @ W2 ; P2 = relu(A_hat @ G2 + b2) ---
    gemm_mfma_kernel<0, 0, 0><<<dim3(512 / 128, GY), 256, 0, stream>>>(
        Q1h, Q1l, W2Th, W2Tl, nullptr, G2f, nullptr, nullptr, NN, 512, 1024);
    aggregate512_kernel<1, 1><<<NN, 128, 0, stream>>>(G2f, P2h, P2l, row_ptr, ed, dinv, b2);

    // --- layer 3: G3 = P2 @ W3 ; D2 = relu(A_hat @ G3 + b3) ---
    gemm_mfma_kernel<0, 0, 0><<<dim3(128 / 128, GY), 256, 0, stream>>>(
        P2h, P2l, W3Th, W3Tl, nullptr, G3f, nullptr, nullptr, NN, 128, 512);
    aggregate128_kernel<1, 1><<<(NN + 3) / 4, 256, 0, stream>>>(G3f, D2, row_ptr, ed, dinv, b3);

    // --- FC + log_softmax ---
    fc_logsoftmax_kernel<<<(NN + 3) / 4, 256, 0, stream>>>(D2, Wfc, bfc, out, NN);
}

// Round 7
// 1859.314 us; speedup vs baseline: 1.0858x; 1.0131x over previous
//
#include <hip/hip_runtime.h>
#include <cstddef>

#define NN 50000
#define EE 1600000

typedef unsigned short ushortT;
typedef short bf16x8 __attribute__((ext_vector_type(8)));
typedef float f32x4 __attribute__((ext_vector_type(4)));
typedef unsigned short us8 __attribute__((ext_vector_type(8)));

__device__ __forceinline__ ushortT f2bf(float x) {  // RNE float->bf16 bits
    unsigned u = __float_as_uint(x);
    u += 0x7fffu + ((u >> 16) & 1u);
    return (ushortT)(u >> 16);
}
__device__ __forceinline__ float bf2f(ushortT h) { return __uint_as_float(((unsigned)h) << 16); }

// ---------------- edge dtype canonicalization ----------------
__global__ void detect_i64_kernel(const int* __restrict__ ei, int* __restrict__ flag) {
    __shared__ int any;
    if (threadIdx.x == 0) any = 0;
    __syncthreads();
    for (int i = threadIdx.x; i < 8192; i += 256)
        if (ei[2 * i + 1] != 0) any = 1;   // benign race
    __syncthreads();
    if (threadIdx.x == 0) *flag = (any ? 0 : 1);  // 1 => int64 layout
}

// fused: canonicalize edges + count in-degree (one pass over edge list)
__global__ void canon_count_kernel(const int* __restrict__ ei, const int* __restrict__ flag,
                                   int* __restrict__ src32, int* __restrict__ dst32,
                                   unsigned* __restrict__ counts) {
    int e = blockIdx.x * blockDim.x + threadIdx.x;
    if (e >= EE) return;
    int s, d;
    if (*flag) {
        s = ei[2 * e];
        d = ei[2 * (EE + e)];
    } else {
        s = ei[e];
        d = ei[EE + e];
    }
    src32[e] = s;
    dst32[e] = d;
    atomicAdd(&counts[d], 1u);
}

// 3-kernel parallel scan over counts[0..n) -> row_ptr (exclusive+1), cursor, dinv
__global__ void scan_part_kernel(const unsigned* __restrict__ counts, unsigned* __restrict__ part, int n) {
    __shared__ unsigned s[256];
    int i = blockIdx.x * 256 + threadIdx.x;
    s[threadIdx.x] = (i < n) ? counts[i] : 0u;
    __syncthreads();
    for (int off = 128; off > 0; off >>= 1) {
        if (threadIdx.x < (unsigned)off) s[threadIdx.x] += s[threadIdx.x + off];
        __syncthreads();
    }
    if (threadIdx.x == 0) part[blockIdx.x] = s[0];
}

__global__ void scan_base_kernel(unsigned* __restrict__ part, int nb) {
    __shared__ unsigned s[256];
    int t = threadIdx.x;
    unsigned v = (t < nb) ? part[t] : 0u;
    s[t] = v;
    __syncthreads();
    for (int off = 1; off < 256; off <<= 1) {
        unsigned a = (t >= off) ? s[t - off] : 0u;
        __syncthreads();
        s[t] += a;
        __syncthreads();
    }
    if (t < nb) part[t] = s[t] - v;  // exclusive
}

__global__ void scan_final_kernel(const unsigned* __restrict__ counts, const unsigned* __restrict__ part,
                                  unsigned* __restrict__ row_ptr, unsigned* __restrict__ cursor,
                                  float* __restrict__ dinv, int n) {
    __shared__ unsigned s[256];
    int b = blockIdx.x, t = threadIdx.x;
    int i = b * 256 + t;
    unsigned v = (i < n) ? counts[i] : 0u;
    s[t] = v;
    __syncthreads();
    for (int off = 1; off < 256; off <<= 1) {
        unsigned a = (t >= off) ? s[t - off] : 0u;
        __syncthreads();
        s[t] += a;
        __syncthreads();
    }
    if (i < n) {
        unsigned incl = s[t] + part[b];
        row_ptr[i + 1] = incl;
        cursor[i] = incl - v;
        dinv[i] = rsqrtf((float)v + 1.0f);  // +1 self-loop
    }
    if (i == 0) row_ptr[0] = 0;
}

// edge record: x = src node, y = float bits of norm weight
__global__ void scatter_kernel(const int* __restrict__ src, const int* __restrict__ dst,
                               const float* __restrict__ dinv, unsigned* __restrict__ cursor,
                               uint2* __restrict__ ed) {
    int e = blockIdx.x * blockDim.x + threadIdx.x;
    if (e >= EE) return;
    int d = dst[e], s = src[e];
    unsigned p = atomicAdd(&cursor[d], 1u);
    uint2 r;
    r.x = (unsigned)s;
    r.y = __float_as_uint(dinv[s] * dinv[d]);
    ed[p] = r;
}

// ---------------- weight transpose + hi/lo bf16 split: W[K][N] -> WT[N][K] ----------------
__global__ void wconv_kernel(const float* __restrict__ W, ushortT* __restrict__ WTh,
                             ushortT* __restrict__ WTl, int K, int N) {
    int idx = blockIdx.x * 256 + threadIdx.x;
    if (idx >= K * N) return;
    int k = idx / N, n = idx - k * N;
    float w = W[idx];
    ushortT h = f2bf(w);
    ushortT l = f2bf(w - bf2f(h));
    WTh[(size_t)n * K + k] = h;
    WTl[(size_t)n * K + k] = l;
}

// ---------------- aggregation C=512 (8-edge ILP batches), fp32 in -> bf16 hi/lo out ----------------
// Measured (r5): pinned at ~3.56 TB/s fabric regardless of CU-side ILP -> L2-miss
// concurrency limit. Kept as-is; treated as floor.
template <int RELU, int BIAS>
__global__ void aggregate512_kernel(const float* __restrict__ F,
                                    ushortT* __restrict__ Oh, ushortT* __restrict__ Ol,
                                    const unsigned* __restrict__ row_ptr, const uint2* __restrict__ ed,
                                    const float* __restrict__ dinv, const float* __restrict__ bias) {
    int node = blockIdx.x;
    int t = threadIdx.x;  // 128 threads x float4 = 512 ch
    float di = dinv[node];
    float dsl = di * di;
    float4 acc = ((const float4*)(F + (size_t)node * 512))[t];
    acc.x *= dsl; acc.y *= dsl; acc.z *= dsl; acc.w *= dsl;
    unsigned k = row_ptr[node], end = row_ptr[node + 1];
    for (; k + 8 <= end; k += 8) {
        uint2 e[8];
#pragma unroll
        for (int j = 0; j < 8; j++) e[j] = ed[k + j];
        float4 f[8];
#pragma unroll
        for (int j = 0; j < 8; j++) f[j] = ((const float4*)(F + (size_t)e[j].x * 512))[t];
#pragma unroll
        for (int j = 0; j < 8; j++) {
            float w = __uint_as_float(e[j].y);
            acc.x += w * f[j].x;
            acc.y += w * f[j].y;
            acc.z += w * f[j].z;
            acc.w += w * f[j].w;
        }
    }
    for (; k < end; k++) {
        uint2 e = ed[k];
        float w = __uint_as_float(e.y);
        float4 f = ((const float4*)(F + (size_t)e.x * 512))[t];
        acc.x += w * f.x; acc.y += w * f.y; acc.z += w * f.z; acc.w += w * f.w;
    }
    if (BIAS) {
        float4 bv = ((const float4*)bias)[t];
        acc.x += bv.x; acc.y += bv.y; acc.z += bv.z; acc.w += bv.w;
    }
    if (RELU) {
        acc.x = fmaxf(acc.x, 0.f); acc.y = fmaxf(acc.y, 0.f);
        acc.z = fmaxf(acc.z, 0.f); acc.w = fmaxf(acc.w, 0.f);
    }
    ushort4 h, l;
    h.x = f2bf(acc.x); l.x = f2bf(acc.x - bf2f(h.x));
    h.y = f2bf(acc.y); l.y = f2bf(acc.y - bf2f(h.y));
    h.z = f2bf(acc.z); l.z = f2bf(acc.z - bf2f(h.z));
    h.w = f2bf(acc.w); l.w = f2bf(acc.w - bf2f(h.w));
    ((ushort4*)(Oh + (size_t)node * 512))[t] = h;
    ((ushort4*)(Ol + (size_t)node * 512))[t] = l;
}

// ---------------- aggregation C=128 (one wave per node, float2/lane, 8-edge batches) ----------------
template <int RELU, int BIAS>
__global__ void aggregate128_kernel(const float* __restrict__ F, float* __restrict__ O,
                                    const unsigned* __restrict__ row_ptr, const uint2* __restrict__ ed,
                                    const float* __restrict__ dinv, const float* __restrict__ bias) {
    int wid = threadIdx.x >> 6;
    int lane = threadIdx.x & 63;
    int node = blockIdx.x * 4 + wid;
    if (node >= NN) return;
    float di = dinv[node];
    float dsl = di * di;
    float2 acc = ((const float2*)(F + (size_t)node * 128))[lane];
    acc.x *= dsl; acc.y *= dsl;
    unsigned k = row_ptr[node], end = row_ptr[node + 1];
    for (; k + 8 <= end; k += 8) {
        uint2 e[8];
#pragma unroll
        for (int j = 0; j < 8; j++) e[j] = ed[k + j];
        float2 f[8];
#pragma unroll
        for (int j = 0; j < 8; j++) f[j] = ((const float2*)(F + (size_t)e[j].x * 128))[lane];
#pragma unroll
        for (int j = 0; j < 8; j++) {
            float w = __uint_as_float(e[j].y);
            acc.x += w * f[j].x;
            acc.y += w * f[j].y;
        }
    }
    for (; k < end; k++) {
        uint2 e = ed[k];
        float w = __uint_as_float(e.y);
        float2 f = ((const float2*)(F + (size_t)e.x * 128))[lane];
        acc.x += w * f.x; acc.y += w * f.y;
    }
    if (BIAS) {
        float2 bv = ((const float2*)bias)[lane];
        acc.x += bv.x; acc.y += bv.y;
    }
    if (RELU) { acc.x = fmaxf(acc.x, 0.f); acc.y = fmaxf(acc.y, 0.f); }
    ((float2*)(O + (size_t)node * 128))[lane] = acc;
}

// ---------------- bf16x3-split MFMA GEMM ----------------
// vs validated r3 kernel:
//  (1) XCD-chunked bijective block swizzle (m204): blocks sharing an A-panel
//      (same m-tile, all n-tiles) become consecutive on ONE XCD -> A re-reads
//      hit that XCD's L2 instead of re-fetching from L3/HBM per n-tile.
//  (2) issue-early staging: next K-step's global loads issued right after the
//      second barrier, overlapping the 48-MFMA compute (reg-staged T14).
// Inner staging/read/MFMA structure unchanged (validated).
template <int OUTMODE, int RELU, int BIAS>  // OUTMODE 0: fp32 C, 1: bf16 hi/lo planes
__global__ __launch_bounds__(256) void gemm_mfma_kernel(
    const ushortT* __restrict__ Ah, const ushortT* __restrict__ Al,
    const ushortT* __restrict__ Bh, const ushortT* __restrict__ Bl,
    const float* __restrict__ bias,
    float* __restrict__ Cf, ushortT* __restrict__ Ch, ushortT* __restrict__ Cl,
    int M, int N, int K) {
    __shared__ ushortT As[2][128][40];  // [plane][row][k], 80B row stride
    __shared__ ushortT Bs[2][128][40];
    int tid = threadIdx.x;
    int lane = tid & 63, wave = tid >> 6;
    int wr = wave >> 1, wc = wave & 1;

    // ---- XCD-chunked bijective swizzle (m204) over the flat grid ----
    int nx = gridDim.x;
    int nwg = nx * gridDim.y;
    int flat = blockIdx.x + nx * blockIdx.y;
    int q = nwg >> 3, r = nwg & 7;
    int xcd = flat & 7, pos = flat >> 3;
    int start = (xcd < r) ? xcd * (q + 1) : r * (q + 1) + (xcd - r) * q;
    int g = start + pos;
    int bm = (g / nx) * 128, bn = (g % nx) * 128;

    int srow = tid >> 1;
    int shalf = (tid & 1) * 16;
    int kg = lane >> 4, lr = lane & 15;

    f32x4 zero4 = {0.f, 0.f, 0.f, 0.f};
    f32x4 acc[4][4];
#pragma unroll
    for (int i = 0; i < 4; i++)
#pragma unroll
        for (int j = 0; j < 4; j++) acc[i][j] = zero4;

    int gm_st = bm + srow;
    const ushortT* pAh = Ah + (size_t)gm_st * K + shalf;
    const ushortT* pAl = Al + (size_t)gm_st * K + shalf;
    const ushortT* pBh = Bh + (size_t)(bn + srow) * K + shalf;
    const ushortT* pBl = Bl + (size_t)(bn + srow) * K + shalf;

    us8 z8 = {0,0,0,0,0,0,0,0};
    us8 ah0 = z8, ah1 = z8, al0 = z8, al1 = z8;
    us8 bh0, bh1, bl0, bl1;
    // prologue: load k0=0
    if (gm_st < M) {
        ah0 = *(const us8*)(pAh);
        ah1 = *(const us8*)(pAh + 8);
        al0 = *(const us8*)(pAl);
        al1 = *(const us8*)(pAl + 8);
    }
    bh0 = *(const us8*)(pBh);
    bh1 = *(const us8*)(pBh + 8);
    bl0 = *(const us8*)(pBl);
    bl1 = *(const us8*)(pBl + 8);

    for (int k0 = 0; k0 < K; k0 += 32) {
        __syncthreads();  // previous iteration's ds_reads done
        *(us8*)&As[0][srow][shalf] = ah0;
        *(us8*)&As[0][srow][shalf + 8] = ah1;
        *(us8*)&As[1][srow][shalf] = al0;
        *(us8*)&As[1][srow][shalf + 8] = al1;
        *(us8*)&Bs[0][srow][shalf] = bh0;
        *(us8*)&Bs[0][srow][shalf + 8] = bh1;
        *(us8*)&Bs[1][srow][shalf] = bl0;
        *(us8*)&Bs[1][srow][shalf + 8] = bl1;
        __syncthreads();

        // issue-early: next K-step's global loads overlap this step's compute
        int kn = k0 + 32;
        if (kn < K) {
            ah0 = ah1 = al0 = al1 = z8;
            if (gm_st < M) {
                ah0 = *(const us8*)(pAh + kn);
                ah1 = *(const us8*)(pAh + kn + 8);
                al0 = *(const us8*)(pAl + kn);
                al1 = *(const us8*)(pAl + kn + 8);
            }
            bh0 = *(const us8*)(pBh + kn);
            bh1 = *(const us8*)(pBh + kn + 8);
            bl0 = *(const us8*)(pBl + kn);
            bl1 = *(const us8*)(pBl + kn + 8);
        }

        bf16x8 afh[4], afl[4], bfh[4], bfl[4];
#pragma unroll
        for (int i = 0; i < 4; i++) {
            int rr = wr * 64 + i * 16 + lr;
            afh[i] = *(const bf16x8*)&As[0][rr][kg * 8];
            afl[i] = *(const bf16x8*)&As[1][rr][kg * 8];
        }
#pragma unroll
        for (int j = 0; j < 4; j++) {
            int c = wc * 64 + j * 16 + lr;
            bfh[j] = *(const bf16x8*)&Bs[0][c][kg * 8];
            bfl[j] = *(const bf16x8*)&Bs[1][c][kg * 8];
        }
#pragma unroll
        for (int i = 0; i < 4; i++)
#pragma unroll
            for (int j = 0; j < 4; j++) {
                acc[i][j] = __builtin_amdgcn_mfma_f32_16x16x32_bf16(afh[i], bfh[j], acc[i][j], 0, 0, 0);
                acc[i][j] = __builtin_amdgcn_mfma_f32_16x16x32_bf16(afh[i], bfl[j], acc[i][j], 0, 0, 0);
                acc[i][j] = __builtin_amdgcn_mfma_f32_16x16x32_bf16(afl[i], bfh[j], acc[i][j], 0, 0, 0);
            }
    }

#pragma unroll
    for (int i = 0; i < 4; i++)
#pragma unroll
        for (int j = 0; j < 4; j++) {
            int gn = bn + wc * 64 + j * 16 + lr;
            float bv = BIAS ? bias[gn] : 0.f;
#pragma unroll
            for (int reg = 0; reg < 4; reg++) {
                int gm = bm + wr * 64 + i * 16 + kg * 4 + reg;
                if (gm < M) {
                    float v = acc[i][j][reg] + bv;
                    if (RELU) v = fmaxf(v, 0.f);
                    if (OUTMODE == 0) {
                        Cf[(size_t)gm * N + gn] = v;
                    } else {
                        ushortT h = f2bf(v);
                        Ch[(size_t)gm * N + gn] = h;
                        Cl[(size_t)gm * N + gn] = f2bf(v - bf2f(h));
                    }
                }
            }
        }
}

// ---------------- FC 128->10 + log_softmax ----------------
__global__ void fc_logsoftmax_kernel(const float* __restrict__ H, const float* __restrict__ Wfc,
                                     const float* __restrict__ bfc, float* __restrict__ out, int M) {
    int wid = threadIdx.x >> 6;
    int lane = threadIdx.x & 63;
    int node = blockIdx.x * 4 + wid;
    if (node >= M) return;
    const float* h = H + (size_t)node * 128;
    float d0 = h[lane], d1 = h[lane + 64];
    float lg[10];
#pragma unroll
    for (int c = 0; c < 10; c++) {
        float s = d0 * Wfc[lane * 10 + c] + d1 * Wfc[(lane + 64) * 10 + c];
#pragma unroll
        for (int o = 1; o < 64; o <<= 1) s += __shfl_xor(s, o, 64);
        lg[c] = s + bfc[c];
    }
    float mx = lg[0];
#pragma unroll
    for (int c = 1; c < 10; c++) mx = fmaxf(mx, lg[c]);
    float se = 0.f;
#pragma unroll
    for (int c = 0; c < 10; c++) se += expf(lg[c] - mx);
    float lse = logf(se) + mx;
    if (lane < 10) {
        float v = 0.f;
#pragma unroll
        for (int c = 0; c < 10; c++)
            if (lane == c) v = lg[c];
        out[(size_t)node * 10 + lane] = v - lse;
    }
}

extern "C" void kernel_launch(void* const* d_in, const int* in_sizes, int n_in,
                              void* d_out, int out_size, void* d_ws, size_t ws_size,
                              hipStream_t stream) {
    const float* x   = (const float*)d_in[0];
    const int*   ei  = (const int*)d_in[1];
    const float* W1  = (const float*)d_in[2];
    const float* b1  = (const float*)d_in[3];
    const float* W2  = (const float*)d_in[4];
    const float* b2  = (const float*)d_in[5];
    const float* W3  = (const float*)d_in[6];
    const float* b3  = (const float*)d_in[7];
    const float* Wfc = (const float*)d_in[8];
    const float* bfc = (const float*)d_in[9];
    float* out = (float*)d_out;

    char* ws = (char*)d_ws;
    size_t off = 0;
    auto alloc = [&](size_t bytes) -> void* {
        void* p = ws + off;
        off = (off + bytes + 255) & ~(size_t)255;
        return p;
    };
    int*      flag    = (int*)alloc(4);
    unsigned* counts  = (unsigned*)alloc((size_t)NN * 4);
    unsigned* row_ptr = (unsigned*)alloc((size_t)(NN + 1) * 4);
    unsigned* cursor  = (unsigned*)alloc((size_t)NN * 4);
    unsigned* part    = (unsigned*)alloc((size_t)256 * 4);
    float*    dinv    = (float*)alloc((size_t)NN * 4);
    int*      src32   = (int*)alloc((size_t)EE * 4);
    int*      dst32   = (int*)alloc((size_t)EE * 4);
    uint2*    ed      = (uint2*)alloc((size_t)EE * 8);
    ushortT*  W1Th    = (ushortT*)alloc((size_t)1024 * 512 * 2);
    ushortT*  W1Tl    = (ushortT*)alloc((size_t)1024 * 512 * 2);
    ushortT*  W2Th    = (ushortT*)alloc((size_t)512 * 1024 * 2);
    ushortT*  W2Tl    = (ushortT*)alloc((size_t)512 * 1024 * 2);
    ushortT*  W3Th    = (ushortT*)alloc((size_t)128 * 512 * 2);
    ushortT*  W3Tl    = (ushortT*)alloc((size_t)128 * 512 * 2);
    char*     bufA    = (char*)alloc((size_t)NN * 1024 * 2 * 2);  // 204.8 MB
    char*     bufB    = (char*)alloc((size_t)NN * 512 * 4);       // 102.4 MB

    // aliased views (sequential lifetimes):
    ushortT* P1h = (ushortT*)bufB;                 // agg1 out planes [NN][512]
    ushortT* P1l = P1h + (size_t)NN * 512;
    ushortT* Q1h = (ushortT*)bufA;                 // gemm1 out planes [NN][1024]
    ushortT* Q1l = Q1h + (size_t)NN * 1024;
    float*   G2f = (float*)bufB;                   // gemm2 out fp32 [NN][512]
    ushortT* P2h = (ushortT*)bufA;                 // agg2 out planes [NN][512]
    ushortT* P2l = P2h + (size_t)NN * 512;
    float*   G3f = (float*)bufB;                   // gemm3 out fp32 [NN][128]
    float*   D2  = (float*)bufA;                   // agg3 out fp32 [NN][128]

    // --- weight conversion ---
    wconv_kernel<<<(512 * 1024 + 255) / 256, 256, 0, stream>>>(W1, W1Th, W1Tl, 512, 1024);
    wconv_kernel<<<(1024 * 512 + 255) / 256, 256, 0, stream>>>(W2, W2Th, W2Tl, 1024, 512);
    wconv_kernel<<<(512 * 128 + 255) / 256, 256, 0, stream>>>(W3, W3Th, W3Tl, 512, 128);

    // --- edges + CSR (fused canon+count; dinv fused into scan_final) ---
    hipMemsetAsync(counts, 0, (size_t)NN * 4, stream);
    detect_i64_kernel<<<1, 256, 0, stream>>>(ei, flag);
    canon_count_kernel<<<(EE + 255) / 256, 256, 0, stream>>>(ei, flag, src32, dst32, counts);
    const int NB = (NN + 255) / 256;  // 196
    scan_part_kernel<<<NB, 256, 0, stream>>>(counts, part, NN);
    scan_base_kernel<<<1, 256, 0, stream>>>(part, NB);
    scan_final_kernel<<<NB, 256, 0, stream>>>(counts, part, row_ptr, cursor, dinv, NN);
    scatter_kernel<<<(EE + 255) / 256, 256, 0, stream>>>(src32, dst32, dinv, cursor, ed);

    const int GY = (NN + 127) / 128;  // 391

    // --- layer 1: P1 = A_hat @ x ; Q1 = relu(P1 @ W1 + b1) ---
    aggregate512_kernel<0, 0><<<NN, 128, 0, stream>>>(x, P1h, P1l, row_ptr, ed, dinv, nullptr);
    gemm_mfma_kernel<1, 1, 1><<<dim3(1024 / 128, GY), 256, 0, stream>>>(
        P1h, P1l, W1Th, W1Tl, b1, nullptr, Q1h, Q1l, NN, 1024, 512);

    // --- layer 2: G2 = Q1 @ W2 ; P2 = relu(A_hat @ G2 + b2) ---
    gemm_mfma_kernel<0, 0, 0><<<dim3(512 / 128, GY), 256, 0, stream>>>(
        Q1h, Q1l, W2Th, W2Tl, nullptr, G2f, nullptr, nullptr, NN, 512, 1024);
    aggregate512_kernel<1, 1><<<NN, 128, 0, stream>>>(G2f, P2h, P2l, row_ptr, ed, dinv, b2);

    // --- layer 3: G3 = P2 @ W3 ; D2 = relu(A_hat @ G3 + b3) ---
    gemm_mfma_kernel<0, 0, 0><<<dim3(128 / 128, GY), 256, 0, stream>>>(
        P2h, P2l, W3Th, W3Tl, nullptr, G3f, nullptr, nullptr, NN, 128, 512);
    aggregate128_kernel<1, 1><<<(NN + 3) / 4, 256, 0, stream>>>(G3f, D2, row_ptr, ed, dinv, b3);

    // --- FC + log_softmax ---
    fc_logsoftmax_kernel<<<(NN + 3) / 4, 256, 0, stream>>>(D2, Wfc, bfc, out, NN);
}

// Round 8
// 1355.655 us; speedup vs baseline: 1.4892x; 1.3715x over previous
//
#include <hip/hip_runtime.h>
#include <hip/hip_fp16.h>
#include <cstddef>

#define NN 50000
#define EE 1600000

typedef unsigned short ushortT;
typedef short bf16x8 __attribute__((ext_vector_type(8)));
typedef float f32x4 __attribute__((ext_vector_type(4)));
typedef unsigned short us8 __attribute__((ext_vector_type(8)));

struct h2x2 { __half2 a, b; };  // 8B: 4 fp16

__device__ __forceinline__ ushortT f2bf(float x) {  // RNE float->bf16 bits
    unsigned u = __float_as_uint(x);
    u += 0x7fffu + ((u >> 16) & 1u);
    return (ushortT)(u >> 16);
}
__device__ __forceinline__ float bf2f(ushortT h) { return __uint_as_float(((unsigned)h) << 16); }

// ---------------- edge dtype canonicalization ----------------
__global__ void detect_i64_kernel(const int* __restrict__ ei, int* __restrict__ flag) {
    __shared__ int any;
    if (threadIdx.x == 0) any = 0;
    __syncthreads();
    for (int i = threadIdx.x; i < 8192; i += 256)
        if (ei[2 * i + 1] != 0) any = 1;   // benign race
    __syncthreads();
    if (threadIdx.x == 0) *flag = (any ? 0 : 1);  // 1 => int64 layout
}

// fused: canonicalize edges + count in-degree (one pass over edge list)
__global__ void canon_count_kernel(const int* __restrict__ ei, const int* __restrict__ flag,
                                   int* __restrict__ src32, int* __restrict__ dst32,
                                   unsigned* __restrict__ counts) {
    int e = blockIdx.x * blockDim.x + threadIdx.x;
    if (e >= EE) return;
    int s, d;
    if (*flag) {
        s = ei[2 * e];
        d = ei[2 * (EE + e)];
    } else {
        s = ei[e];
        d = ei[EE + e];
    }
    src32[e] = s;
    dst32[e] = d;
    atomicAdd(&counts[d], 1u);
}

// 3-kernel parallel scan over counts[0..n) -> row_ptr (exclusive+1), cursor, dinv
__global__ void scan_part_kernel(const unsigned* __restrict__ counts, unsigned* __restrict__ part, int n) {
    __shared__ unsigned s[256];
    int i = blockIdx.x * 256 + threadIdx.x;
    s[threadIdx.x] = (i < n) ? counts[i] : 0u;
    __syncthreads();
    for (int off = 128; off > 0; off >>= 1) {
        if (threadIdx.x < (unsigned)off) s[threadIdx.x] += s[threadIdx.x + off];
        __syncthreads();
    }
    if (threadIdx.x == 0) part[blockIdx.x] = s[0];
}

__global__ void scan_base_kernel(unsigned* __restrict__ part, int nb) {
    __shared__ unsigned s[256];
    int t = threadIdx.x;
    unsigned v = (t < nb) ? part[t] : 0u;
    s[t] = v;
    __syncthreads();
    for (int off = 1; off < 256; off <<= 1) {
        unsigned a = (t >= off) ? s[t - off] : 0u;
        __syncthreads();
        s[t] += a;
        __syncthreads();
    }
    if (t < nb) part[t] = s[t] - v;  // exclusive
}

__global__ void scan_final_kernel(const unsigned* __restrict__ counts, const unsigned* __restrict__ part,
                                  unsigned* __restrict__ row_ptr, unsigned* __restrict__ cursor,
                                  float* __restrict__ dinv, int n) {
    __shared__ unsigned s[256];
    int b = blockIdx.x, t = threadIdx.x;
    int i = b * 256 + t;
    unsigned v = (i < n) ? counts[i] : 0u;
    s[t] = v;
    __syncthreads();
    for (int off = 1; off < 256; off <<= 1) {
        unsigned a = (t >= off) ? s[t - off] : 0u;
        __syncthreads();
        s[t] += a;
        __syncthreads();
    }
    if (i < n) {
        unsigned incl = s[t] + part[b];
        row_ptr[i + 1] = incl;
        cursor[i] = incl - v;
        dinv[i] = rsqrtf((float)v + 1.0f);  // +1 self-loop
    }
    if (i == 0) row_ptr[0] = 0;
}

// edge record: x = src node, y = float bits of norm weight
__global__ void scatter_kernel(const int* __restrict__ src, const int* __restrict__ dst,
                               const float* __restrict__ dinv, unsigned* __restrict__ cursor,
                               uint2* __restrict__ ed) {
    int e = blockIdx.x * blockDim.x + threadIdx.x;
    if (e >= EE) return;
    int d = dst[e], s = src[e];
    unsigned p = atomicAdd(&cursor[d], 1u);
    uint2 r;
    r.x = (unsigned)s;
    r.y = __float_as_uint(dinv[s] * dinv[d]);
    ed[p] = r;
}

// ---------------- fp32 -> fp16 conversion (x matrix) ----------------
__global__ void f32_to_f16_kernel(const float* __restrict__ in, __half* __restrict__ out, int n4) {
    int i = blockIdx.x * 256 + threadIdx.x;  // i indexes groups of 4
    if (i >= n4) return;
    float4 v = ((const float4*)in)[i];
    h2x2 o;
    o.a = __floats2half2_rn(v.x, v.y);
    o.b = __floats2half2_rn(v.z, v.w);
    ((h2x2*)out)[i] = o;
}

// ---------------- weight transpose + hi/lo bf16 split: W[K][N] -> WT[N][K] ----------------
__global__ void wconv_kernel(const float* __restrict__ W, ushortT* __restrict__ WTh,
                             ushortT* __restrict__ WTl, int K, int N) {
    int idx = blockIdx.x * 256 + threadIdx.x;
    if (idx >= K * N) return;
    int k = idx / N, n = idx - k * N;
    float w = W[idx];
    ushortT h = f2bf(w);
    ushortT l = f2bf(w - bf2f(h));
    WTh[(size_t)n * K + k] = h;
    WTl[(size_t)n * K + k] = l;
}

// ---------------- aggregation C=512, fp16 in (8B/lane/edge), bf16 hi/lo out ----------------
// r8: input gathered as fp16 -> halves lines-per-edge (16->8 of 128B). The r5/r7
// measurements show a ~3.55 TB/s fabric floor invariant to CU-side ILP; bytes
// are the only lever. Accumulation stays fp32.
template <int RELU, int BIAS>
__global__ void aggregate512_kernel(const __half* __restrict__ F,
                                    ushortT* __restrict__ Oh, ushortT* __restrict__ Ol,
                                    const unsigned* __restrict__ row_ptr, const uint2* __restrict__ ed,
                                    const float* __restrict__ dinv, const float* __restrict__ bias) {
    int node = blockIdx.x;
    int t = threadIdx.x;  // 128 threads x 4 fp16 = 512 ch
    float di = dinv[node];
    float dsl = di * di;
    h2x2 sv = ((const h2x2*)(F + (size_t)node * 512))[t];
    float2 s0 = __half22float2(sv.a), s1 = __half22float2(sv.b);
    float4 acc;
    acc.x = dsl * s0.x; acc.y = dsl * s0.y; acc.z = dsl * s1.x; acc.w = dsl * s1.y;
    unsigned k = row_ptr[node], end = row_ptr[node + 1];
    for (; k + 8 <= end; k += 8) {
        uint2 e[8];
#pragma unroll
        for (int j = 0; j < 8; j++) e[j] = ed[k + j];
        h2x2 f[8];
#pragma unroll
        for (int j = 0; j < 8; j++) f[j] = ((const h2x2*)(F + (size_t)e[j].x * 512))[t];
#pragma unroll
        for (int j = 0; j < 8; j++) {
            float w = __uint_as_float(e[j].y);
            float2 f0 = __half22float2(f[j].a), f1 = __half22float2(f[j].b);
            acc.x += w * f0.x;
            acc.y += w * f0.y;
            acc.z += w * f1.x;
            acc.w += w * f1.y;
        }
    }
    for (; k < end; k++) {
        uint2 e = ed[k];
        float w = __uint_as_float(e.y);
        h2x2 fv = ((const h2x2*)(F + (size_t)e.x * 512))[t];
        float2 f0 = __half22float2(fv.a), f1 = __half22float2(fv.b);
        acc.x += w * f0.x; acc.y += w * f0.y; acc.z += w * f1.x; acc.w += w * f1.y;
    }
    if (BIAS) {
        float4 bv = ((const float4*)bias)[t];
        acc.x += bv.x; acc.y += bv.y; acc.z += bv.z; acc.w += bv.w;
    }
    if (RELU) {
        acc.x = fmaxf(acc.x, 0.f); acc.y = fmaxf(acc.y, 0.f);
        acc.z = fmaxf(acc.z, 0.f); acc.w = fmaxf(acc.w, 0.f);
    }
    ushort4 h, l;
    h.x = f2bf(acc.x); l.x = f2bf(acc.x - bf2f(h.x));
    h.y = f2bf(acc.y); l.y = f2bf(acc.y - bf2f(h.y));
    h.z = f2bf(acc.z); l.z = f2bf(acc.z - bf2f(h.z));
    h.w = f2bf(acc.w); l.w = f2bf(acc.w - bf2f(h.w));
    ((ushort4*)(Oh + (size_t)node * 512))[t] = h;
    ((ushort4*)(Ol + (size_t)node * 512))[t] = l;
}

// ---------------- aggregation C=128 (one wave/node), fp16 in, fp32 out ----------------
template <int RELU, int BIAS>
__global__ void aggregate128_kernel(const __half* __restrict__ F, float* __restrict__ O,
                                    const unsigned* __restrict__ row_ptr, const uint2* __restrict__ ed,
                                    const float* __restrict__ dinv, const float* __restrict__ bias) {
    int wid = threadIdx.x >> 6;
    int lane = threadIdx.x & 63;
    int node = blockIdx.x * 4 + wid;
    if (node >= NN) return;
    float di = dinv[node];
    float dsl = di * di;
    __half2 sv = ((const __half2*)(F + (size_t)node * 128))[lane];
    float2 sf = __half22float2(sv);
    float2 acc;
    acc.x = dsl * sf.x; acc.y = dsl * sf.y;
    unsigned k = row_ptr[node], end = row_ptr[node + 1];
    for (; k + 8 <= end; k += 8) {
        uint2 e[8];
#pragma unroll
        for (int j = 0; j < 8; j++) e[j] = ed[k + j];
        __half2 f[8];
#pragma unroll
        for (int j = 0; j < 8; j++) f[j] = ((const __half2*)(F + (size_t)e[j].x * 128))[lane];
#pragma unroll
        for (int j = 0; j < 8; j++) {
            float w = __uint_as_float(e[j].y);
            float2 ff = __half22float2(f[j]);
            acc.x += w * ff.x;
            acc.y += w * ff.y;
        }
    }
    for (; k < end; k++) {
        uint2 e = ed[k];
        float w = __uint_as_float(e.y);
        float2 ff = __half22float2(((const __half2*)(F + (size_t)e.x * 128))[lane]);
        acc.x += w * ff.x; acc.y += w * ff.y;
    }
    if (BIAS) {
        float2 bv = ((const float2*)bias)[lane];
        acc.x += bv.x; acc.y += bv.y;
    }
    if (RELU) { acc.x = fmaxf(acc.x, 0.f); acc.y = fmaxf(acc.y, 0.f); }
    ((float2*)(O + (size_t)node * 128))[lane] = acc;
}

// ---------------- bf16x3-split MFMA GEMM ----------------
// OUTMODE 0: fp32 Cf | 1: bf16 hi/lo planes Ch/Cl | 2: fp16 Cg
template <int OUTMODE, int RELU, int BIAS>
__global__ __launch_bounds__(256) void gemm_mfma_kernel(
    const ushortT* __restrict__ Ah, const ushortT* __restrict__ Al,
    const ushortT* __restrict__ Bh, const ushortT* __restrict__ Bl,
    const float* __restrict__ bias,
    float* __restrict__ Cf, ushortT* __restrict__ Ch, ushortT* __restrict__ Cl,
    __half* __restrict__ Cg,
    int M, int N, int K) {
    __shared__ ushortT As[2][128][40];  // [plane][row][k], 80B row stride
    __shared__ ushortT Bs[2][128][40];
    int tid = threadIdx.x;
    int lane = tid & 63, wave = tid >> 6;
    int wr = wave >> 1, wc = wave & 1;

    // XCD-chunked bijective swizzle (m204) over the flat grid
    int nx = gridDim.x;
    int nwg = nx * gridDim.y;
    int flat = blockIdx.x + nx * blockIdx.y;
    int q = nwg >> 3, r = nwg & 7;
    int xcd = flat & 7, pos = flat >> 3;
    int start = (xcd < r) ? xcd * (q + 1) : r * (q + 1) + (xcd - r) * q;
    int g = start + pos;
    int bm = (g / nx) * 128, bn = (g % nx) * 128;

    int srow = tid >> 1;
    int shalf = (tid & 1) * 16;
    int kg = lane >> 4, lr = lane & 15;

    f32x4 zero4 = {0.f, 0.f, 0.f, 0.f};
    f32x4 acc[4][4];
#pragma unroll
    for (int i = 0; i < 4; i++)
#pragma unroll
        for (int j = 0; j < 4; j++) acc[i][j] = zero4;

    int gm_st = bm + srow;
    const ushortT* pAh = Ah + (size_t)gm_st * K + shalf;
    const ushortT* pAl = Al + (size_t)gm_st * K + shalf;
    const ushortT* pBh = Bh + (size_t)(bn + srow) * K + shalf;
    const ushortT* pBl = Bl + (size_t)(bn + srow) * K + shalf;

    us8 z8 = {0,0,0,0,0,0,0,0};
    us8 ah0 = z8, ah1 = z8, al0 = z8, al1 = z8;
    us8 bh0, bh1, bl0, bl1;
    if (gm_st < M) {
        ah0 = *(const us8*)(pAh);
        ah1 = *(const us8*)(pAh + 8);
        al0 = *(const us8*)(pAl);
        al1 = *(const us8*)(pAl + 8);
    }
    bh0 = *(const us8*)(pBh);
    bh1 = *(const us8*)(pBh + 8);
    bl0 = *(const us8*)(pBl);
    bl1 = *(const us8*)(pBl + 8);

    for (int k0 = 0; k0 < K; k0 += 32) {
        __syncthreads();
        *(us8*)&As[0][srow][shalf] = ah0;
        *(us8*)&As[0][srow][shalf + 8] = ah1;
        *(us8*)&As[1][srow][shalf] = al0;
        *(us8*)&As[1][srow][shalf + 8] = al1;
        *(us8*)&Bs[0][srow][shalf] = bh0;
        *(us8*)&Bs[0][srow][shalf + 8] = bh1;
        *(us8*)&Bs[1][srow][shalf] = bl0;
        *(us8*)&Bs[1][srow][shalf + 8] = bl1;
        __syncthreads();

        int kn = k0 + 32;
        if (kn < K) {  // issue-early: overlap next loads with MFMA
            ah0 = ah1 = al0 = al1 = z8;
            if (gm_st < M) {
                ah0 = *(const us8*)(pAh + kn);
                ah1 = *(const us8*)(pAh + kn + 8);
                al0 = *(const us8*)(pAl + kn);
                al1 = *(const us8*)(pAl + kn + 8);
            }
            bh0 = *(const us8*)(pBh + kn);
            bh1 = *(const us8*)(pBh + kn + 8);
            bl0 = *(const us8*)(pBl + kn);
            bl1 = *(const us8*)(pBl + kn + 8);
        }

        bf16x8 afh[4], afl[4], bfh[4], bfl[4];
#pragma unroll
        for (int i = 0; i < 4; i++) {
            int rr = wr * 64 + i * 16 + lr;
            afh[i] = *(const bf16x8*)&As[0][rr][kg * 8];
            afl[i] = *(const bf16x8*)&As[1][rr][kg * 8];
        }
#pragma unroll
        for (int j = 0; j < 4; j++) {
            int c = wc * 64 + j * 16 + lr;
            bfh[j] = *(const bf16x8*)&Bs[0][c][kg * 8];
            bfl[j] = *(const bf16x8*)&Bs[1][c][kg * 8];
        }
#pragma unroll
        for (int i = 0; i < 4; i++)
#pragma unroll
            for (int j = 0; j < 4; j++) {
                acc[i][j] = __builtin_amdgcn_mfma_f32_16x16x32_bf16(afh[i], bfh[j], acc[i][j], 0, 0, 0);
                acc[i][j] = __builtin_amdgcn_mfma_f32_16x16x32_bf16(afh[i], bfl[j], acc[i][j], 0, 0, 0);
                acc[i][j] = __builtin_amdgcn_mfma_f32_16x16x32_bf16(afl[i], bfh[j], acc[i][j], 0, 0, 0);
            }
    }

#pragma unroll
    for (int i = 0; i < 4; i++)
#pragma unroll
        for (int j = 0; j < 4; j++) {
            int gn = bn + wc * 64 + j * 16 + lr;
            float bv = BIAS ? bias[gn] : 0.f;
#pragma unroll
            for (int reg = 0; reg < 4; reg++) {
                int gm = bm + wr * 64 + i * 16 + kg * 4 + reg;
                if (gm < M) {
                    float v = acc[i][j][reg] + bv;
                    if (RELU) v = fmaxf(v, 0.f);
                    if (OUTMODE == 0) {
                        Cf[(size_t)gm * N + gn] = v;
                    } else if (OUTMODE == 1) {
                        ushortT h = f2bf(v);
                        Ch[(size_t)gm * N + gn] = h;
                        Cl[(size_t)gm * N + gn] = f2bf(v - bf2f(h));
                    } else {
                        Cg[(size_t)gm * N + gn] = __float2half_rn(v);
                    }
                }
            }
        }
}

// ---------------- FC 128->10 + log_softmax ----------------
__global__ void fc_logsoftmax_kernel(const float* __restrict__ H, const float* __restrict__ Wfc,
                                     const float* __restrict__ bfc, float* __restrict__ out, int M) {
    int wid = threadIdx.x >> 6;
    int lane = threadIdx.x & 63;
    int node = blockIdx.x * 4 + wid;
    if (node >= M) return;
    const float* h = H + (size_t)node * 128;
    float d0 = h[lane], d1 = h[lane + 64];
    float lg[10];
#pragma unroll
    for (int c = 0; c < 10; c++) {
        float s = d0 * Wfc[lane * 10 + c] + d1 * Wfc[(lane + 64) * 10 + c];
#pragma unroll
        for (int o = 1; o < 64; o <<= 1) s += __shfl_xor(s, o, 64);
        lg[c] = s + bfc[c];
    }
    float mx = lg[0];
#pragma unroll
    for (int c = 1; c < 10; c++) mx = fmaxf(mx, lg[c]);
    float se = 0.f;
#pragma unroll
    for (int c = 0; c < 10; c++) se += expf(lg[c] - mx);
    float lse = logf(se) + mx;
    if (lane < 10) {
        float v = 0.f;
#pragma unroll
        for (int c = 0; c < 10; c++)
            if (lane == c) v = lg[c];
        out[(size_t)node * 10 + lane] = v - lse;
    }
}

extern "C" void kernel_launch(void* const* d_in, const int* in_sizes, int n_in,
                              void* d_out, int out_size, void* d_ws, size_t ws_size,
                              hipStream_t stream) {
    const float* x   = (const float*)d_in[0];
    const int*   ei  = (const int*)d_in[1];
    const float* W1  = (const float*)d_in[2];
    const float* b1  = (const float*)d_in[3];
    const float* W2  = (const float*)d_in[4];
    const float* b2  = (const float*)d_in[5];
    const float* W3  = (const float*)d_in[6];
    const float* b3  = (const float*)d_in[7];
    const float* Wfc = (const float*)d_in[8];
    const float* bfc = (const float*)d_in[9];
    float* out = (float*)d_out;

    char* ws = (char*)d_ws;
    size_t off = 0;
    auto alloc = [&](size_t bytes) -> void* {
        void* p = ws + off;
        off = (off + bytes + 255) & ~(size_t)255;
        return p;
    };
    int*      flag    = (int*)alloc(4);
    unsigned* counts  = (unsigned*)alloc((size_t)NN * 4);
    unsigned* row_ptr = (unsigned*)alloc((size_t)(NN + 1) * 4);
    unsigned* cursor  = (unsigned*)alloc((size_t)NN * 4);
    unsigned* part    = (unsigned*)alloc((size_t)256 * 4);
    float*    dinv    = (float*)alloc((size_t)NN * 4);
    int*      src32   = (int*)alloc((size_t)EE * 4);
    int*      dst32   = (int*)alloc((size_t)EE * 4);
    uint2*    ed      = (uint2*)alloc((size_t)EE * 8);
    ushortT*  W1Th    = (ushortT*)alloc((size_t)1024 * 512 * 2);
    ushortT*  W1Tl    = (ushortT*)alloc((size_t)1024 * 512 * 2);
    ushortT*  W2Th    = (ushortT*)alloc((size_t)512 * 1024 * 2);
    ushortT*  W2Tl    = (ushortT*)alloc((size_t)512 * 1024 * 2);
    ushortT*  W3Th    = (ushortT*)alloc((size_t)128 * 512 * 2);
    ushortT*  W3Tl    = (ushortT*)alloc((size_t)128 * 512 * 2);
    char*     bufA    = (char*)alloc((size_t)NN * 1024 * 2 * 2);  // 204.8 MB
    char*     bufB    = (char*)alloc((size_t)NN * 512 * 4);       // 102.4 MB

    // aliased views (sequential lifetimes):
    __half*  xh  = (__half*)(bufA + (size_t)NN * 1024 * 2);  // x fp16, in Q1l region (dead until GEMM1)
    ushortT* P1h = (ushortT*)bufB;                 // agg1 out planes [NN][512]
    ushortT* P1l = P1h + (size_t)NN * 512;
    ushortT* Q1h = (ushortT*)bufA;                 // gemm1 out planes [NN][1024]
    ushortT* Q1l = Q1h + (size_t)NN * 1024;
    __half*  G2h16 = (__half*)bufB;                // gemm2 out fp16 [NN][512]
    ushortT* P2h = (ushortT*)bufA;                 // agg2 out planes [NN][512]
    ushortT* P2l = P2h + (size_t)NN * 512;
    __half*  G3h16 = (__half*)bufB;                // gemm3 out fp16 [NN][128]
    float*   D2  = (float*)bufA;                   // agg3 out fp32 [NN][128]

    // --- weight conversion ---
    wconv_kernel<<<(512 * 1024 + 255) / 256, 256, 0, stream>>>(W1, W1Th, W1Tl, 512, 1024);
    wconv_kernel<<<(1024 * 512 + 255) / 256, 256, 0, stream>>>(W2, W2Th, W2Tl, 1024, 512);
    wconv_kernel<<<(512 * 128 + 255) / 256, 256, 0, stream>>>(W3, W3Th, W3Tl, 512, 128);

    // --- edges + CSR ---
    hipMemsetAsync(counts, 0, (size_t)NN * 4, stream);
    detect_i64_kernel<<<1, 256, 0, stream>>>(ei, flag);
    canon_count_kernel<<<(EE + 255) / 256, 256, 0, stream>>>(ei, flag, src32, dst32, counts);
    const int NB = (NN + 255) / 256;  // 196
    scan_part_kernel<<<NB, 256, 0, stream>>>(counts, part, NN);
    scan_base_kernel<<<1, 256, 0, stream>>>(part, NB);
    scan_final_kernel<<<NB, 256, 0, stream>>>(counts, part, row_ptr, cursor, dinv, NN);
    scatter_kernel<<<(EE + 255) / 256, 256, 0, stream>>>(src32, dst32, dinv, cursor, ed);

    const int GY = (NN + 127) / 128;  // 391

    // --- layer 1: xh = fp16(x); P1 = A_hat @ xh ; Q1 = relu(P1 @ W1 + b1) ---
    f32_to_f16_kernel<<<(NN * 512 / 4 + 255) / 256, 256, 0, stream>>>(x, xh, NN * 512 / 4);
    aggregate512_kernel<0, 0><<<NN, 128, 0, stream>>>(xh, P1h, P1l, row_ptr, ed, dinv, nullptr);
    gemm_mfma_kernel<1, 1, 1><<<dim3(1024 / 128, GY), 256, 0, stream>>>(
        P1h, P1l, W1Th, W1Tl, b1, nullptr, Q1h, Q1l, nullptr, NN, 1024, 512);

    // --- layer 2: G2 = fp16(Q1 @ W2) ; P2 = relu(A_hat @ G2 + b2) ---
    gemm_mfma_kernel<2, 0, 0><<<dim3(512 / 128, GY), 256, 0, stream>>>(
        Q1h, Q1l, W2Th, W2Tl, nullptr, nullptr, nullptr, nullptr, G2h16, NN, 512, 1024);
    aggregate512_kernel<1, 1><<<NN, 128, 0, stream>>>(G2h16, P2h, P2l, row_ptr, ed, dinv, b2);

    // --- layer 3: G3 = fp16(P2 @ W3) ; D2 = relu(A_hat @ G3 + b3) ---
    gemm_mfma_kernel<2, 0, 0><<<dim3(128 / 128, GY), 256, 0, stream>>>(
        P2h, P2l, W3Th, W3Tl, nullptr, nullptr, nullptr, nullptr, G3h16, NN, 128, 512);
    aggregate128_kernel<1, 1><<<(NN + 3) / 4, 256, 0, stream>>>(G3h16, D2, row_ptr, ed, dinv, b3);

    // --- FC + log_softmax ---
    fc_logsoftmax_kernel<<<(NN + 3) / 4, 256, 0, stream>>>(D2, Wfc, bfc, out, NN);
}

// Round 10
// 1310.871 us; speedup vs baseline: 1.5401x; 1.0342x over previous
//
#include <hip/hip_runtime.h>
#include <hip/hip_fp16.h>
#include <cstddef>

#define NN 50000
#define EE 1600000

typedef unsigned short ushortT;
typedef short bf16x8 __attribute__((ext_vector_type(8)));
typedef float f32x4 __attribute__((ext_vector_type(4)));
typedef unsigned short us8 __attribute__((ext_vector_type(8)));

struct h2x2 { __half2 a, b; };  // 8B: 4 fp16

__device__ __forceinline__ ushortT f2bf(float x) {  // RNE float->bf16 bits
    unsigned u = __float_as_uint(x);
    u += 0x7fffu + ((u >> 16) & 1u);
    return (ushortT)(u >> 16);
}
__device__ __forceinline__ float bf2f(ushortT h) { return __uint_as_float(((unsigned)h) << 16); }

// ---------------- edge dtype canonicalization ----------------
__global__ void detect_i64_kernel(const int* __restrict__ ei, int* __restrict__ flag) {
    __shared__ int any;
    if (threadIdx.x == 0) any = 0;
    __syncthreads();
    for (int i = threadIdx.x; i < 8192; i += 256)
        if (ei[2 * i + 1] != 0) any = 1;   // benign race
    __syncthreads();
    if (threadIdx.x == 0) *flag = (any ? 0 : 1);  // 1 => int64 layout
}

// fused: canonicalize edges + count in-degree
__global__ void canon_count_kernel(const int* __restrict__ ei, const int* __restrict__ flag,
                                   int* __restrict__ src32, int* __restrict__ dst32,
                                   unsigned* __restrict__ counts) {
    int e = blockIdx.x * blockDim.x + threadIdx.x;
    if (e >= EE) return;
    int s, d;
    if (*flag) {
        s = ei[2 * e];
        d = ei[2 * (EE + e)];
    } else {
        s = ei[e];
        d = ei[EE + e];
    }
    src32[e] = s;
    dst32[e] = d;
    atomicAdd(&counts[d], 1u);
}

// 3-kernel parallel scan -> row_ptr, cursor, dinv
__global__ void scan_part_kernel(const unsigned* __restrict__ counts, unsigned* __restrict__ part, int n) {
    __shared__ unsigned s[256];
    int i = blockIdx.x * 256 + threadIdx.x;
    s[threadIdx.x] = (i < n) ? counts[i] : 0u;
    __syncthreads();
    for (int off = 128; off > 0; off >>= 1) {
        if (threadIdx.x < (unsigned)off) s[threadIdx.x] += s[threadIdx.x + off];
        __syncthreads();
    }
    if (threadIdx.x == 0) part[blockIdx.x] = s[0];
}

__global__ void scan_base_kernel(unsigned* __restrict__ part, int nb) {
    __shared__ unsigned s[256];
    int t = threadIdx.x;
    unsigned v = (t < nb) ? part[t] : 0u;
    s[t] = v;
    __syncthreads();
    for (int off = 1; off < 256; off <<= 1) {
        unsigned a = (t >= off) ? s[t - off] : 0u;
        __syncthreads();
        s[t] += a;
        __syncthreads();
    }
    if (t < nb) part[t] = s[t] - v;  // exclusive
}

__global__ void scan_final_kernel(const unsigned* __restrict__ counts, const unsigned* __restrict__ part,
                                  unsigned* __restrict__ row_ptr, unsigned* __restrict__ cursor,
                                  float* __restrict__ dinv, int n) {
    __shared__ unsigned s[256];
    int b = blockIdx.x, t = threadIdx.x;
    int i = b * 256 + t;
    unsigned v = (i < n) ? counts[i] : 0u;
    s[t] = v;
    __syncthreads();
    for (int off = 1; off < 256; off <<= 1) {
        unsigned a = (t >= off) ? s[t - off] : 0u;
        __syncthreads();
        s[t] += a;
        __syncthreads();
    }
    if (i < n) {
        unsigned incl = s[t] + part[b];
        row_ptr[i + 1] = incl;
        cursor[i] = incl - v;
        dinv[i] = rsqrtf((float)v + 1.0f);  // +1 self-loop
    }
    if (i == 0) row_ptr[0] = 0;
}

// edge record: x = src node, y = float bits of norm weight
__global__ void scatter_kernel(const int* __restrict__ src, const int* __restrict__ dst,
                               const float* __restrict__ dinv, unsigned* __restrict__ cursor,
                               uint2* __restrict__ ed) {
    int e = blockIdx.x * blockDim.x + threadIdx.x;
    if (e >= EE) return;
    int d = dst[e], s = src[e];
    unsigned p = atomicAdd(&cursor[d], 1u);
    uint2 r;
    r.x = (unsigned)s;
    r.y = __float_as_uint(dinv[s] * dinv[d]);
    ed[p] = r;
}

// ---------------- fp32 -> fp16 conversion (x matrix) ----------------
__global__ void f32_to_f16_kernel(const float* __restrict__ in, __half* __restrict__ out, int n4) {
    int i = blockIdx.x * 256 + threadIdx.x;
    if (i >= n4) return;
    float4 v = ((const float4*)in)[i];
    h2x2 o;
    o.a = __floats2half2_rn(v.x, v.y);
    o.b = __floats2half2_rn(v.z, v.w);
    ((h2x2*)out)[i] = o;
}

// ---------------- weight transpose + hi/lo bf16 split: W[K][N] -> WT[N][K] ----------------
__global__ void wconv_kernel(const float* __restrict__ W, ushortT* __restrict__ WTh,
                             ushortT* __restrict__ WTl, int K, int N) {
    int idx = blockIdx.x * 256 + threadIdx.x;
    if (idx >= K * N) return;
    int k = idx / N, n = idx - k * N;
    float w = W[idx];
    ushortT h = f2bf(w);
    ushortT l = f2bf(w - bf2f(h));
    WTh[(size_t)n * K + k] = h;
    WTl[(size_t)n * K + k] = l;
}

// ---------------- aggregation C=512, fp16 in, bf16 hi/lo out (validated r8) ----------------
template <int RELU, int BIAS>
__global__ void aggregate512_kernel(const __half* __restrict__ F,
                                    ushortT* __restrict__ Oh, ushortT* __restrict__ Ol,
                                    const unsigned* __restrict__ row_ptr, const uint2* __restrict__ ed,
                                    const float* __restrict__ dinv, const float* __restrict__ bias) {
    int node = blockIdx.x;
    int t = threadIdx.x;  // 128 threads x 4 fp16 = 512 ch
    float di = dinv[node];
    float dsl = di * di;
    h2x2 sv = ((const h2x2*)(F + (size_t)node * 512))[t];
    float2 s0 = __half22float2(sv.a), s1 = __half22float2(sv.b);
    float4 acc;
    acc.x = dsl * s0.x; acc.y = dsl * s0.y; acc.z = dsl * s1.x; acc.w = dsl * s1.y;
    unsigned k = row_ptr[node], end = row_ptr[node + 1];
    for (; k + 8 <= end; k += 8) {
        uint2 e[8];
#pragma unroll
        for (int j = 0; j < 8; j++) e[j] = ed[k + j];
        h2x2 f[8];
#pragma unroll
        for (int j = 0; j < 8; j++) f[j] = ((const h2x2*)(F + (size_t)e[j].x * 512))[t];
#pragma unroll
        for (int j = 0; j < 8; j++) {
            float w = __uint_as_float(e[j].y);
            float2 f0 = __half22float2(f[j].a), f1 = __half22float2(f[j].b);
            acc.x += w * f0.x;
            acc.y += w * f0.y;
            acc.z += w * f1.x;
            acc.w += w * f1.y;
        }
    }
    for (; k < end; k++) {
        uint2 e = ed[k];
        float w = __uint_as_float(e.y);
        h2x2 fv = ((const h2x2*)(F + (size_t)e.x * 512))[t];
        float2 f0 = __half22float2(fv.a), f1 = __half22float2(fv.b);
        acc.x += w * f0.x; acc.y += w * f0.y; acc.z += w * f1.x; acc.w += w * f1.y;
    }
    if (BIAS) {
        float4 bv = ((const float4*)bias)[t];
        acc.x += bv.x; acc.y += bv.y; acc.z += bv.z; acc.w += bv.w;
    }
    if (RELU) {
        acc.x = fmaxf(acc.x, 0.f); acc.y = fmaxf(acc.y, 0.f);
        acc.z = fmaxf(acc.z, 0.f); acc.w = fmaxf(acc.w, 0.f);
    }
    ushort4 h, l;
    h.x = f2bf(acc.x); l.x = f2bf(acc.x - bf2f(h.x));
    h.y = f2bf(acc.y); l.y = f2bf(acc.y - bf2f(h.y));
    h.z = f2bf(acc.z); l.z = f2bf(acc.z - bf2f(h.z));
    h.w = f2bf(acc.w); l.w = f2bf(acc.w - bf2f(h.w));
    ((ushort4*)(Oh + (size_t)node * 512))[t] = h;
    ((ushort4*)(Ol + (size_t)node * 512))[t] = l;
}

// ---------------- fused: agg128 (fp16 in) + FC 128->10 + log_softmax ----------------
// One wave per node; acc.x/acc.y hold channels {2*lane, 2*lane+1}.
__global__ void agg128_fc_ls_kernel(const __half* __restrict__ F,
                                    const unsigned* __restrict__ row_ptr, const uint2* __restrict__ ed,
                                    const float* __restrict__ dinv, const float* __restrict__ bias,
                                    const float* __restrict__ Wfc, const float* __restrict__ bfc,
                                    float* __restrict__ out) {
    int wid = threadIdx.x >> 6;
    int lane = threadIdx.x & 63;
    int node = blockIdx.x * 4 + wid;  // NN % 4 == 0: all waves full
    float di = dinv[node];
    float dsl = di * di;
    __half2 sv = ((const __half2*)(F + (size_t)node * 128))[lane];
    float2 sf = __half22float2(sv);
    float2 acc;
    acc.x = dsl * sf.x; acc.y = dsl * sf.y;
    unsigned k = row_ptr[node], end = row_ptr[node + 1];
    for (; k + 8 <= end; k += 8) {
        uint2 e[8];
#pragma unroll
        for (int j = 0; j < 8; j++) e[j] = ed[k + j];
        __half2 f[8];
#pragma unroll
        for (int j = 0; j < 8; j++) f[j] = ((const __half2*)(F + (size_t)e[j].x * 128))[lane];
#pragma unroll
        for (int j = 0; j < 8; j++) {
            float w = __uint_as_float(e[j].y);
            float2 ff = __half22float2(f[j]);
            acc.x += w * ff.x;
            acc.y += w * ff.y;
        }
    }
    for (; k < end; k++) {
        uint2 e = ed[k];
        float w = __uint_as_float(e.y);
        float2 ff = __half22float2(((const __half2*)(F + (size_t)e.x * 128))[lane]);
        acc.x += w * ff.x; acc.y += w * ff.y;
    }
    float2 bv = ((const float2*)bias)[lane];
    acc.x = fmaxf(acc.x + bv.x, 0.f);
    acc.y = fmaxf(acc.y + bv.y, 0.f);
    // FC: logits[c] = sum_d h[d]*Wfc[d][c] + bfc[c]
    float lg[10];
#pragma unroll
    for (int c = 0; c < 10; c++) {
        float s = acc.x * Wfc[(2 * lane) * 10 + c] + acc.y * Wfc[(2 * lane + 1) * 10 + c];
#pragma unroll
        for (int o = 1; o < 64; o <<= 1) s += __shfl_xor(s, o, 64);
        lg[c] = s + bfc[c];
    }
    float mx = lg[0];
#pragma unroll
    for (int c = 1; c < 10; c++) mx = fmaxf(mx, lg[c]);
    float se = 0.f;
#pragma unroll
    for (int c = 0; c < 10; c++) se += expf(lg[c] - mx);
    float lse = logf(se) + mx;
    if (lane < 10) {
        float v = 0.f;
#pragma unroll
        for (int c = 0; c < 10; c++)
            if (lane == c) v = lg[c];
        out[(size_t)node * 10 + lane] = v - lse;
    }
}

// ---------------- bf16x3-split MFMA GEMM ----------------
// LDS layout [plane][row][32] (64B rows, no pad) + st_16x32-style XOR swizzle
// on 16B chunks: chunk' = chunk ^ (((row>>3)&1)<<1), applied on BOTH staging
// writes and fragment reads (rule #21: same involution both sides).
// Old 80B-stride layout put all fragment-read lanes on banks %4==0 (8-way,
// SQ_LDS_BANK_CONFLICT=25.6M); padding cannot fix a 16B-aligned stride.
// OUTMODE 0: fp32 Cf | 1: bf16 hi/lo planes Ch/Cl | 2: fp16 Cg
template <int OUTMODE, int RELU, int BIAS>
__global__ __launch_bounds__(256) void gemm_mfma_kernel(
    const ushortT* __restrict__ Ah, const ushortT* __restrict__ Al,
    const ushortT* __restrict__ Bh, const ushortT* __restrict__ Bl,
    const float* __restrict__ bias,
    float* __restrict__ Cf, ushortT* __restrict__ Ch, ushortT* __restrict__ Cl,
    __half* __restrict__ Cg,
    int M, int N, int K) {
    __shared__ ushortT As[2][128][32];  // [plane][row][k], 64B rows, swizzled chunks
    __shared__ ushortT Bs[2][128][32];
    int tid = threadIdx.x;
    int lane = tid & 63, wave = tid >> 6;
    int wr = wave >> 1, wc = wave & 1;

    // XCD-chunked bijective swizzle (m204) over the flat grid
    int nx = gridDim.x;
    int nwg = nx * gridDim.y;
    int flat = blockIdx.x + nx * blockIdx.y;
    int q = nwg >> 3, r = nwg & 7;
    int xcd = flat & 7, pos = flat >> 3;
    int start = (xcd < r) ? xcd * (q + 1) : r * (q + 1) + (xcd - r) * q;
    int g = start + pos;
    int bm = (g / nx) * 128, bn = (g % nx) * 128;

    int srow = tid >> 1;
    int sh = tid & 1;           // k-half: chunks {2sh, 2sh+1}
    int kg = lane >> 4, lr = lane & 15;

    // staging write chunk positions (swizzled)
    int wsz = ((srow >> 3) & 1) << 1;
    int wc0 = (2 * sh + 0) ^ wsz;
    int wc1 = (2 * sh + 1) ^ wsz;

    f32x4 zero4 = {0.f, 0.f, 0.f, 0.f};
    f32x4 acc[4][4];
#pragma unroll
    for (int i = 0; i < 4; i++)
#pragma unroll
        for (int j = 0; j < 4; j++) acc[i][j] = zero4;

    int gm_st = bm + srow;
    int shalf = sh * 16;
    const ushortT* pAh = Ah + (size_t)gm_st * K + shalf;
    const ushortT* pAl = Al + (size_t)gm_st * K + shalf;
    const ushortT* pBh = Bh + (size_t)(bn + srow) * K + shalf;
    const ushortT* pBl = Bl + (size_t)(bn + srow) * K + shalf;

    us8 z8 = {0,0,0,0,0,0,0,0};
    us8 ah0 = z8, ah1 = z8, al0 = z8, al1 = z8;
    us8 bh0, bh1, bl0, bl1;
    if (gm_st < M) {
        ah0 = *(const us8*)(pAh);
        ah1 = *(const us8*)(pAh + 8);
        al0 = *(const us8*)(pAl);
        al1 = *(const us8*)(pAl + 8);
    }
    bh0 = *(const us8*)(pBh);
    bh1 = *(const us8*)(pBh + 8);
    bl0 = *(const us8*)(pBl);
    bl1 = *(const us8*)(pBl + 8);

    for (int k0 = 0; k0 < K; k0 += 32) {
        __syncthreads();
        *(us8*)&As[0][srow][wc0 * 8] = ah0;
        *(us8*)&As[0][srow][wc1 * 8] = ah1;
        *(us8*)&As[1][srow][wc0 * 8] = al0;
        *(us8*)&As[1][srow][wc1 * 8] = al1;
        *(us8*)&Bs[0][srow][wc0 * 8] = bh0;
        *(us8*)&Bs[0][srow][wc1 * 8] = bh1;
        *(us8*)&Bs[1][srow][wc0 * 8] = bl0;
        *(us8*)&Bs[1][srow][wc1 * 8] = bl1;
        __syncthreads();

        int kn = k0 + 32;
        if (kn < K) {  // issue-early: overlap next loads with MFMA
            ah0 = ah1 = al0 = al1 = z8;
            if (gm_st < M) {
                ah0 = *(const us8*)(pAh + kn);
                ah1 = *(const us8*)(pAh + kn + 8);
                al0 = *(const us8*)(pAl + kn);
                al1 = *(const us8*)(pAl + kn + 8);
            }
            bh0 = *(const us8*)(pBh + kn);
            bh1 = *(const us8*)(pBh + kn + 8);
            bl0 = *(const us8*)(pBl + kn);
            bl1 = *(const us8*)(pBl + kn + 8);
        }

        bf16x8 afh[4], afl[4], bfh[4], bfl[4];
#pragma unroll
        for (int i = 0; i < 4; i++) {
            int rr = wr * 64 + i * 16 + lr;
            int ck = (kg ^ (((rr >> 3) & 1) << 1)) * 8;
            afh[i] = *(const bf16x8*)&As[0][rr][ck];
            afl[i] = *(const bf16x8*)&As[1][rr][ck];
        }
#pragma unroll
        for (int j = 0; j < 4; j++) {
            int cc = wc * 64 + j * 16 + lr;
            int ck = (kg ^ (((cc >> 3) & 1) << 1)) * 8;
            bfh[j] = *(const bf16x8*)&Bs[0][cc][ck];
            bfl[j] = *(const bf16x8*)&Bs[1][cc][ck];
        }
#pragma unroll
        for (int i = 0; i < 4; i++)
#pragma unroll
            for (int j = 0; j < 4; j++) {
                acc[i][j] = __builtin_amdgcn_mfma_f32_16x16x32_bf16(afh[i], bfh[j], acc[i][j], 0, 0, 0);
                acc[i][j] = __builtin_amdgcn_mfma_f32_16x16x32_bf16(afh[i], bfl[j], acc[i][j], 0, 0, 0);
                acc[i][j] = __builtin_amdgcn_mfma_f32_16x16x32_bf16(afl[i], bfh[j], acc[i][j], 0, 0, 0);
            }
    }

#pragma unroll
    for (int i = 0; i < 4; i++)
#pragma unroll
        for (int j = 0; j < 4; j++) {
            int gn = bn + wc * 64 + j * 16 + lr;
            float bv = BIAS ? bias[gn] : 0.f;
#pragma unroll
            for (int reg = 0; reg < 4; reg++) {
                int gm = bm + wr * 64 + i * 16 + kg * 4 + reg;
                if (gm < M) {
                    float v = acc[i][j][reg] + bv;
                    if (RELU) v = fmaxf(v, 0.f);
                    if (OUTMODE == 0) {
                        Cf[(size_t)gm * N + gn] = v;
                    } else if (OUTMODE == 1) {
                        ushortT h = f2bf(v);
                        Ch[(size_t)gm * N + gn] = h;
                        Cl[(size_t)gm * N + gn] = f2bf(v - bf2f(h));
                    } else {
                        Cg[(size_t)gm * N + gn] = __float2half_rn(v);
                    }
                }
            }
        }
}

extern "C" void kernel_launch(void* const* d_in, const int* in_sizes, int n_in,
                              void* d_out, int out_size, void* d_ws, size_t ws_size,
                              hipStream_t stream) {
    const float* x   = (const float*)d_in[0];
    const int*   ei  = (const int*)d_in[1];
    const float* W1  = (const float*)d_in[2];
    const float* b1  = (const float*)d_in[3];
    const float* W2  = (const float*)d_in[4];
    const float* b2  = (const float*)d_in[5];
    const float* W3  = (const float*)d_in[6];
    const float* b3  = (const float*)d_in[7];
    const float* Wfc = (const float*)d_in[8];
    const float* bfc = (const float*)d_in[9];
    float* out = (float*)d_out;

    char* ws = (char*)d_ws;
    size_t off = 0;
    auto alloc = [&](size_t bytes) -> void* {
        void* p = ws + off;
        off = (off + bytes + 255) & ~(size_t)255;
        return p;
    };
    int*      flag    = (int*)alloc(4);
    unsigned* counts  = (unsigned*)alloc((size_t)NN * 4);
    unsigned* row_ptr = (unsigned*)alloc((size_t)(NN + 1) * 4);
    unsigned* cursor  = (unsigned*)alloc((size_t)NN * 4);
    unsigned* part    = (unsigned*)alloc((size_t)256 * 4);
    float*    dinv    = (float*)alloc((size_t)NN * 4);
    int*      src32   = (int*)alloc((size_t)EE * 4);
    int*      dst32   = (int*)alloc((size_t)EE * 4);
    uint2*    ed      = (uint2*)alloc((size_t)EE * 8);
    ushortT*  W1Th    = (ushortT*)alloc((size_t)1024 * 512 * 2);
    ushortT*  W1Tl    = (ushortT*)alloc((size_t)1024 * 512 * 2);
    ushortT*  W2Th    = (ushortT*)alloc((size_t)512 * 1024 * 2);
    ushortT*  W2Tl    = (ushortT*)alloc((size_t)512 * 1024 * 2);
    ushortT*  W3Th    = (ushortT*)alloc((size_t)128 * 512 * 2);
    ushortT*  W3Tl    = (ushortT*)alloc((size_t)128 * 512 * 2);
    char*     bufA    = (char*)alloc((size_t)NN * 1024 * 2 * 2);  // 204.8 MB
    char*     bufB    = (char*)alloc((size_t)NN * 512 * 4);       // 102.4 MB

    // aliased views (sequential lifetimes):
    __half*  xh  = (__half*)(bufA + (size_t)NN * 1024 * 2);  // x fp16, in Q1l region
    ushortT* P1h = (ushortT*)bufB;                 // agg1 out planes [NN][512]
    ushortT* P1l = P1h + (size_t)NN * 512;
    ushortT* Q1h = (ushortT*)bufA;                 // gemm1 out planes [NN][1024]
    ushortT* Q1l = Q1h + (size_t)NN * 1024;
    __half*  G2h16 = (__half*)bufB;                // gemm2 out fp16 [NN][512]
    ushortT* P2h = (ushortT*)bufA;                 // agg2 out planes [NN][512]
    ushortT* P2l = P2h + (size_t)NN * 512;
    __half*  G3h16 = (__half*)bufB;                // gemm3 out fp16 [NN][128]

    // --- weight conversion ---
    wconv_kernel<<<(512 * 1024 + 255) / 256, 256, 0, stream>>>(W1, W1Th, W1Tl, 512, 1024);
    wconv_kernel<<<(1024 * 512 + 255) / 256, 256, 0, stream>>>(W2, W2Th, W2Tl, 1024, 512);
    wconv_kernel<<<(512 * 128 + 255) / 256, 256, 0, stream>>>(W3, W3Th, W3Tl, 512, 128);

    // --- edges + CSR ---
    hipMemsetAsync(counts, 0, (size_t)NN * 4, stream);
    detect_i64_kernel<<<1, 256, 0, stream>>>(ei, flag);
    canon_count_kernel<<<(EE + 255) / 256, 256, 0, stream>>>(ei, flag, src32, dst32, counts);
    const int NB = (NN + 255) / 256;  // 196
    scan_part_kernel<<<NB, 256, 0, stream>>>(counts, part, NN);
    scan_base_kernel<<<1, 256, 0, stream>>>(part, NB);
    scan_final_kernel<<<NB, 256, 0, stream>>>(counts, part, row_ptr, cursor, dinv, NN);
    scatter_kernel<<<(EE + 255) / 256, 256, 0, stream>>>(src32, dst32, dinv, cursor, ed);

    const int GY = (NN + 127) / 128;  // 391

    // --- layer 1: xh = fp16(x); P1 = A_hat @ xh ; Q1 = relu(P1 @ W1 + b1) ---
    f32_to_f16_kernel<<<(NN * 512 / 4 + 255) / 256, 256, 0, stream>>>(x, xh, NN * 512 / 4);
    aggregate512_kernel<0, 0><<<NN, 128, 0, stream>>>(xh, P1h, P1l, row_ptr, ed, dinv, nullptr);
    gemm_mfma_kernel<1, 1, 1><<<dim3(1024 / 128, GY), 256, 0, stream>>>(
        P1h, P1l, W1Th, W1Tl, b1, nullptr, Q1h, Q1l, nullptr, NN, 1024, 512);

    // --- layer 2: G2 = fp16(Q1 @ W2) ; P2 = relu(A_hat @ G2 + b2) ---
    gemm_mfma_kernel<2, 0, 0><<<dim3(512 / 128, GY), 256, 0, stream>>>(
        Q1h, Q1l, W2Th, W2Tl, nullptr, nullptr, nullptr, nullptr, G2h16, NN, 512, 1024);
    aggregate512_kernel<1, 1><<<NN, 128, 0, stream>>>(G2h16, P2h, P2l, row_ptr, ed, dinv, b2);

    // --- layer 3: G3 = fp16(P2 @ W3) ; fused agg128 + FC + log_softmax ---
    gemm_mfma_kernel<2, 0, 0><<<dim3(128 / 128, GY), 256, 0, stream>>>(
        P2h, P2l, W3Th, W3Tl, nullptr, nullptr, nullptr, nullptr, G3h16, NN, 128, 512);
    agg128_fc_ls_kernel<<<NN / 4, 256, 0, stream>>>(G3h16, row_ptr, ed, dinv, b3, Wfc, bfc, out);
}